// Round 1
// baseline (4525.702 us; speedup 1.0000x reference)
//
#include <hip/hip_runtime.h>
#include <cstdint>

#define NN 50000
#define NE 800000
#define NG 64
#define HD 128
#define FT 64
#define NLAYERS 3

// ---------- float <-> ordered-uint encoding for atomic min/max ----------
__device__ __forceinline__ unsigned fenc(float f){
    unsigned u = __float_as_uint(f);
    return (u & 0x80000000u) ? ~u : (u | 0x80000000u);
}
__device__ __forceinline__ float fdec(unsigned e){
    unsigned u = (e & 0x80000000u) ? (e & 0x7FFFFFFFu) : ~e;
    return __uint_as_float(u);
}

__global__ void k_reset_minmax(unsigned* mn, unsigned* mx){
    int i = threadIdx.x;
    if (i < NG){ mn[i] = 0xFFFFFFFFu; mx[i] = 0u; }
}

__global__ void k_counts(const int* __restrict__ batch, int* counts){
    int i = blockIdx.x*blockDim.x + threadIdx.x;
    if (i < NN) atomicAdd(&counts[batch[i]], 1);
}

__global__ void k_seg_minmax(const float* __restrict__ v, const int* __restrict__ batch,
                             unsigned* mn, unsigned* mx){
    int i = blockIdx.x*blockDim.x + threadIdx.x;
    if (i < NN){
        unsigned e = fenc(v[i]);
        int g = batch[i];
        atomicMin(&mn[g], e);
        atomicMax(&mx[g], e);
    }
}

__global__ void k_seg_norm(const float* __restrict__ v, const int* __restrict__ batch,
                           const unsigned* __restrict__ mn, const unsigned* __restrict__ mx,
                           float* __restrict__ out, int thresh){
    int i = blockIdx.x*blockDim.x + threadIdx.x;
    if (i < NN){
        int g = batch[i];
        float lo = fdec(mn[g]), hi = fdec(mx[g]);
        float t = (v[i] - lo) / (hi - lo + 1e-8f);
        if (thresh && t < 0.1f) t = 0.f;
        out[i] = t;
    }
}

// Fold imp_proj into init_W: W0 is (FT+1) x HD, b0 = init_b + pb @ init_W[FT:]
__global__ void k_fold_init(const float* __restrict__ pW, const float* __restrict__ pb,
                            const float* __restrict__ iW, const float* __restrict__ ib,
                            float* __restrict__ W0, float* __restrict__ b0){
    int j = threadIdx.x;
    for (int k = 0; k < FT; ++k) W0[k*HD + j] = iW[k*HD + j];
    float w2 = 0.f, b2 = 0.f;
    for (int k = 0; k < HD; ++k){
        float w = iW[(FT + k)*HD + j];
        w2 += pW[k]*w;
        b2 += pb[k]*w;
    }
    W0[FT*HD + j] = w2;
    b0[j] = ib[j] + b2;
}

// ---------- node GEMM: out(N,128) = [A | B | scal] @ W + bias ----------
// mode 0: plain.  mode 1: gate epilogue (A==conv): out = sig(z)*conv + (1-sig(z))*hprev
#define NT 16
__global__ __launch_bounds__(128) void k_gemm(
    const float* __restrict__ A, int Ka,
    const float* __restrict__ B, int Kb,
    const float* __restrict__ scal,
    const float* __restrict__ W,
    const float* __restrict__ bias,
    const float* __restrict__ hprev,
    float* __restrict__ out,
    int mode)
{
    __shared__ float lds[NT][256];
    __shared__ float scs[NT];
    const int Kt = Ka + Kb;
    const int base = blockIdx.x * NT;     // NN % NT == 0, no tail
    const int tid = threadIdx.x;
    for (int t = 0; t < NT; ++t){
        int node = base + t;
        for (int k = tid; k < Kt; k += 128){
            float v;
            if (k < Ka) v = A[(size_t)node*Ka + k];
            else        v = B[(size_t)node*Kb + (k - Ka)];
            lds[t][k] = v;
        }
    }
    if (tid < NT) scs[tid] = scal ? scal[base + tid] : 0.f;
    __syncthreads();

    float acc[NT];
    #pragma unroll
    for (int t = 0; t < NT; ++t) acc[t] = 0.f;
    const int j = tid;
    for (int k = 0; k < Kt; ++k){
        float w = W[k*HD + j];
        #pragma unroll
        for (int t = 0; t < NT; ++t) acc[t] = fmaf(lds[t][k], w, acc[t]);
    }
    if (scal){
        float w = W[Kt*HD + j];
        #pragma unroll
        for (int t = 0; t < NT; ++t) acc[t] = fmaf(scs[t], w, acc[t]);
    }
    float bj = bias ? bias[j] : 0.f;
    for (int t = 0; t < NT; ++t){
        int node = base + t;
        float z = acc[t] + bj;
        if (mode == 0){
            out[(size_t)node*HD + j] = z;
        } else {
            float g = 1.f/(1.f + expf(-z));
            float c = lds[t][j];                         // conv value (A==conv, Ka==HD)
            float hp = hprev[(size_t)node*HD + j];
            out[(size_t)node*HD + j] = g*c + (1.f - g)*hp;
        }
    }
}

// ---------- CSR build (by dst) ----------
__global__ void k_deg(const int* __restrict__ dst, int* deg){
    int e = blockIdx.x*blockDim.x + threadIdx.x;
    if (e < NE) atomicAdd(&deg[dst[e]], 1);
}

__global__ void k_scan(const int* __restrict__ deg, int* __restrict__ rowstart){
    __shared__ int buf[1024];
    __shared__ int carry;
    if (threadIdx.x == 0) carry = 0;
    __syncthreads();
    for (int base = 0; base < NN; base += 1024){
        int i = base + (int)threadIdx.x;
        int v = (i < NN) ? deg[i] : 0;
        buf[threadIdx.x] = v;
        __syncthreads();
        for (int off = 1; off < 1024; off <<= 1){
            int t = (threadIdx.x >= (unsigned)off) ? buf[threadIdx.x - off] : 0;
            __syncthreads();
            buf[threadIdx.x] += t;
            __syncthreads();
        }
        if (i < NN) rowstart[i] = carry + buf[threadIdx.x] - v;   // exclusive
        __syncthreads();
        if (threadIdx.x == 0) carry += buf[1023];
        __syncthreads();
    }
    if (threadIdx.x == 0) rowstart[NN] = carry;
}

__global__ void k_copy_int(const int* __restrict__ a, int* __restrict__ b, int n){
    int i = blockIdx.x*blockDim.x + threadIdx.x;
    if (i < n) b[i] = a[i];
}

__global__ void k_fill(const int* __restrict__ src, const int* __restrict__ dst,
                       int* cursor, int* __restrict__ csr){
    int e = blockIdx.x*blockDim.x + threadIdx.x;
    if (e < NE){
        int d = dst[e];
        int p = atomicAdd(&cursor[d], 1);
        csr[p] = src[e];
    }
}

__global__ void k_aggregate(const float* __restrict__ hm, const int* __restrict__ rowstart,
                            const int* __restrict__ csr, float* __restrict__ aggr){
    int node = blockIdx.x*2 + (threadIdx.x >> 7);
    int j = threadIdx.x & 127;
    if (node >= NN) return;
    float acc = 0.f;
    int e0 = rowstart[node], e1 = rowstart[node + 1];
    for (int e = e0; e < e1; ++e){
        int s = csr[e];
        acc += hm[(size_t)s*HD + j];
    }
    aggr[(size_t)node*HD + j] = acc;
}

// prop = out @ prop_W + prop_b ; impnew = 0.9*imp + 0.1*prop
__global__ void k_prop_imp(const float* __restrict__ outv, const float* __restrict__ pW,
                           const float* __restrict__ pb, const float* __restrict__ imp,
                           float* __restrict__ impnew){
    int gid = blockIdx.x*blockDim.x + threadIdx.x;
    int wave = gid >> 6;
    int lane = threadIdx.x & 63;
    if (wave >= NN) return;
    float a = outv[(size_t)wave*HD + lane]*pW[lane]
            + outv[(size_t)wave*HD + 64 + lane]*pW[64 + lane];
    for (int off = 32; off > 0; off >>= 1) a += __shfl_down(a, off);
    if (lane == 0) impnew[wave] = 0.9f*imp[wave] + 0.1f*(a + pb[0]);
}

// ---------- per-graph column reductions (batch is contiguous runs) ----------
#define CHUNK 256
__global__ void k_colsum(const float* __restrict__ v, const int* __restrict__ batch,
                         float* __restrict__ sums){
    int j = threadIdx.x;
    int start = blockIdx.x * CHUNK;
    if (start >= NN) return;
    int end = min(start + CHUNK, NN);
    int curg = batch[start];
    float acc = 0.f;
    for (int i = start; i < end; ++i){
        int g = batch[i];
        if (g != curg){ atomicAdd(&sums[curg*HD + j], acc); acc = 0.f; curg = g; }
        acc += v[(size_t)i*HD + j];
    }
    atomicAdd(&sums[curg*HD + j], acc);
}

__global__ void k_colvar(const float* __restrict__ v, const int* __restrict__ batch,
                         const float* __restrict__ sums, const int* __restrict__ counts,
                         const float* __restrict__ na, float* __restrict__ vsums){
    int j = threadIdx.x;
    int start = blockIdx.x * CHUNK;
    if (start >= NN) return;
    int end = min(start + CHUNK, NN);
    float aj = na[j];
    int curg = batch[start];
    float m = aj * sums[curg*HD + j] / (float)counts[curg];
    float acc = 0.f;
    for (int i = start; i < end; ++i){
        int g = batch[i];
        if (g != curg){
            atomicAdd(&vsums[curg*HD + j], acc); acc = 0.f; curg = g;
            m = aj * sums[curg*HD + j] / (float)counts[curg];
        }
        float t = v[(size_t)i*HD + j] - m;
        acc += t*t;
    }
    atomicAdd(&vsums[curg*HD + j], acc);
}

__global__ void k_norm_fin(const float* __restrict__ v, const int* __restrict__ batch,
                           const float* __restrict__ sums, const float* __restrict__ vsums,
                           const int* __restrict__ counts,
                           const float* __restrict__ nw, const float* __restrict__ nb,
                           const float* __restrict__ na, float* __restrict__ hout){
    int idx = blockIdx.x*blockDim.x + threadIdx.x;
    int i = idx >> 7, j = idx & 127;
    if (i >= NN) return;
    int g = batch[i];
    float cnt = (float)counts[g];
    float mean = sums[g*HD + j] / cnt;
    float var  = vsums[g*HD + j] / cnt;
    float t = v[(size_t)i*HD + j] - na[j]*mean;
    float r = nw[j]*t / sqrtf(var + 1e-5f) + nb[j];
    hout[(size_t)i*HD + j] = r > 0.f ? r : 0.f;
}

// logits[g] = (segsum h)[g] @ final_W / cnt[g] + final_b
__global__ void k_final_logits(const float* __restrict__ gsum, const int* __restrict__ counts,
                               const float* __restrict__ fW, const float* __restrict__ fb,
                               float* __restrict__ logits){
    int g = blockIdx.x, o = threadIdx.x;   // 64 blocks x 32 threads
    float acc = 0.f;
    for (int jj = 0; jj < HD; ++jj) acc += gsum[g*HD + jj]*fW[jj*32 + o];
    logits[g*32 + o] = acc/(float)counts[g] + fb[o];
}

__global__ void k_add(const float* __restrict__ a, const float* __restrict__ b,
                      float* __restrict__ c){
    int i = blockIdx.x*blockDim.x + threadIdx.x;
    if (i < NN) c[i] = a[i] + b[i];
}

extern "C" void kernel_launch(void* const* d_in, const int* in_sizes, int n_in,
                              void* d_out, int out_size, void* d_ws, size_t ws_size,
                              hipStream_t stream){
    const float* x    = (const float*)d_in[0];
    const float* imp0 = (const float*)d_in[2];
    const float* pW   = (const float*)d_in[3];
    const float* pb   = (const float*)d_in[4];
    const float* iW   = (const float*)d_in[5];
    const float* ib   = (const float*)d_in[6];
    const float* msgW = (const float*)d_in[7];
    const float* msgb = (const float*)d_in[8];
    const float* updW = (const float*)d_in[9];
    const float* updb = (const float*)d_in[10];
    const float* gWt  = (const float*)d_in[11];
    const float* gb   = (const float*)d_in[12];
    const float* prW  = (const float*)d_in[13];
    const float* prb  = (const float*)d_in[14];
    const float* nw   = (const float*)d_in[15];
    const float* nb   = (const float*)d_in[16];
    const float* na   = (const float*)d_in[17];
    const float* fW   = (const float*)d_in[18];
    const float* fb   = (const float*)d_in[19];
    const int* eidx   = (const int*)d_in[20];
    const int* batch  = (const int*)d_in[21];
    const int* esrc = eidx;
    const int* edst = eidx + NE;
    float* outp = (float*)d_out;

    char* w = (char*)d_ws;
    size_t off = 0;
    auto alloc = [&](size_t bytes)->char*{
        char* p = w + off;
        off += (bytes + 255) & ~(size_t)255;
        return p;
    };
    float* h     = (float*)alloc((size_t)NN*HD*4);
    float* bufA  = (float*)alloc((size_t)NN*HD*4);
    float* bufB  = (float*)alloc((size_t)NN*HD*4);
    float* ta    = (float*)alloc((size_t)NN*4);
    float* tb    = (float*)alloc((size_t)NN*4);
    float* imp   = (float*)alloc((size_t)NN*4);
    float* W0    = (float*)alloc((size_t)(FT+1)*HD*4);
    float* b0    = (float*)alloc((size_t)HD*4);
    float* gsum  = (float*)alloc((size_t)NG*HD*4);
    float* gsum2 = (float*)alloc((size_t)NG*HD*4);
    unsigned* mn = (unsigned*)alloc((size_t)NG*4);
    unsigned* mx = (unsigned*)alloc((size_t)NG*4);
    int* counts  = (int*)alloc((size_t)NG*4);
    int* deg     = (int*)alloc((size_t)NN*4);
    int* rowst   = (int*)alloc((size_t)(NN+1)*4);
    int* cursor  = (int*)alloc((size_t)NN*4);
    int* csr     = (int*)alloc((size_t)NE*4);

    // graph sizes
    hipMemsetAsync(counts, 0, NG*4, stream);
    k_counts<<<196, 256, 0, stream>>>(batch, counts);

    // CSR by dst (once; reused for all 3 layers)
    hipMemsetAsync(deg, 0, NN*4, stream);
    k_deg<<<3125, 256, 0, stream>>>(edst, deg);
    k_scan<<<1, 1024, 0, stream>>>(deg, rowst);
    k_copy_int<<<196, 256, 0, stream>>>(rowst, cursor, NN);
    k_fill<<<3125, 256, 0, stream>>>(esrc, edst, cursor, csr);

    // importance = normalize(imp0)
    k_reset_minmax<<<1, 64, 0, stream>>>(mn, mx);
    k_seg_minmax<<<196, 256, 0, stream>>>(imp0, batch, mn, mx);
    k_seg_norm<<<196, 256, 0, stream>>>(imp0, batch, mn, mx, imp, 0);

    // h = [x, imp_emb] @ init_W + init_b  (imp_proj folded)
    k_fold_init<<<1, 128, 0, stream>>>(pW, pb, iW, ib, W0, b0);
    k_gemm<<<3125, 128, 0, stream>>>(x, FT, nullptr, 0, imp, W0, b0, nullptr, h, 0);

    for (int l = 0; l < NLAYERS; ++l){
        const float* mWl = msgW + (size_t)l*HD*HD;
        const float* uWl = updW + (size_t)l*2*HD*HD;
        const float* gWl = gWt  + (size_t)l*(HD+1)*HD;
        // hm = h @ msg_W + msg_b  (aggr of msg == scatter-sum of hm[src])
        k_gemm<<<3125, 128, 0, stream>>>(h, HD, nullptr, 0, nullptr, mWl, msgb + l*HD, nullptr, bufA, 0);
        k_aggregate<<<25000, 256, 0, stream>>>(bufA, rowst, csr, bufB);
        // conv = [h, aggr] @ upd_W + upd_b   (in-place over aggr: rows staged in LDS first)
        k_gemm<<<3125, 128, 0, stream>>>(h, HD, bufB, HD, nullptr, uWl, updb + l*HD, nullptr, bufB, 0);
        // gate + out fused:  out = sig([conv, imp]@gate_W + gate_b)*conv + (1-..)*h
        k_gemm<<<3125, 128, 0, stream>>>(bufB, HD, nullptr, 0, imp, gWl, gb + l*HD, h, bufB, 1);
        // prop + importance decay
        k_prop_imp<<<12500, 256, 0, stream>>>(bufB, prW + (size_t)l*HD, prb + l, imp, ta);
        // imp = norm(ta); thresh; imp = norm(...)
        k_reset_minmax<<<1, 64, 0, stream>>>(mn, mx);
        k_seg_minmax<<<196, 256, 0, stream>>>(ta, batch, mn, mx);
        k_seg_norm<<<196, 256, 0, stream>>>(ta, batch, mn, mx, tb, 1);
        k_reset_minmax<<<1, 64, 0, stream>>>(mn, mx);
        k_seg_minmax<<<196, 256, 0, stream>>>(tb, batch, mn, mx);
        k_seg_norm<<<196, 256, 0, stream>>>(tb, batch, mn, mx, imp, 0);
        // graph norm -> h = relu(...)
        hipMemsetAsync(gsum,  0, NG*HD*4, stream);
        hipMemsetAsync(gsum2, 0, NG*HD*4, stream);
        k_colsum<<<196, 128, 0, stream>>>(bufB, batch, gsum);
        k_colvar<<<196, 128, 0, stream>>>(bufB, batch, gsum, counts, na + l*HD, gsum2);
        k_norm_fin<<<25000, 256, 0, stream>>>(bufB, batch, gsum, gsum2, counts,
                                              nw + l*HD, nb + l*HD, na + l*HD, h);
    }

    // logits
    hipMemsetAsync(gsum, 0, NG*HD*4, stream);
    k_colsum<<<196, 128, 0, stream>>>(h, batch, gsum);
    k_final_logits<<<64, 32, 0, stream>>>(gsum, counts, fW, fb, outp);

    // final_importance = normalize(imp0 + importance)
    k_add<<<196, 256, 0, stream>>>(imp0, imp, ta);
    k_reset_minmax<<<1, 64, 0, stream>>>(mn, mx);
    k_seg_minmax<<<196, 256, 0, stream>>>(ta, batch, mn, mx);
    k_seg_norm<<<196, 256, 0, stream>>>(ta, batch, mn, mx, outp + NG*32, 0);
}

// Round 2
// 2008.375 us; speedup vs baseline: 2.2534x; 2.2534x over previous
//
#include <hip/hip_runtime.h>
#include <cstdint>

#define NN 50000
#define NE 800000
#define NG 64
#define HD 128
#define FT 64
#define NLAYERS 3

// ---------- graph boundaries (batch is sorted contiguous runs) ----------
__global__ void k_gbounds(const int* __restrict__ batch, int* __restrict__ gstart){
    int i = blockIdx.x*blockDim.x + threadIdx.x;
    if (i >= NN) return;
    int g = batch[i];
    if (i == 0){ for (int q = 0; q <= g; ++q) gstart[q] = 0; }
    else { int gp = batch[i-1]; for (int q = gp+1; q <= g; ++q) gstart[q] = i; }
    if (i == NN-1){ for (int q = g+1; q <= NG; ++q) gstart[q] = NN; }
}

__global__ void k_counts_b(const int* __restrict__ gstart, int* __restrict__ counts){
    int g = threadIdx.x;
    if (g < NG) counts[g] = gstart[g+1] - gstart[g];
}

// ---------- block-wide min/max reduce helper (256 threads = 4 waves) ----------
__device__ __forceinline__ void block_minmax(float lmn, float lmx, float* red,
                                             float& omn, float& omx){
    #pragma unroll
    for (int off = 32; off > 0; off >>= 1){
        lmn = fminf(lmn, __shfl_xor(lmn, off));
        lmx = fmaxf(lmx, __shfl_xor(lmx, off));
    }
    int wave = threadIdx.x >> 6;
    if ((threadIdx.x & 63) == 0){ red[wave] = lmn; red[4+wave] = lmx; }
    __syncthreads();
    omn = fminf(fminf(red[0], red[1]), fminf(red[2], red[3]));
    omx = fmaxf(fmaxf(red[4], red[5]), fmaxf(red[6], red[7]));
    __syncthreads();
}

// ---------- fused per-graph normalize (one block per graph, zero atomics) ----
// chain==0: out = normalize(va [+ vb])
// chain==1: t = normalize(va); t = (t<0.1 ? 0 : t); out = normalize(t)
__global__ __launch_bounds__(256) void k_norm_graph(
    const float* __restrict__ va, const float* __restrict__ vb,
    const int* __restrict__ gstart, float* __restrict__ out, int chain)
{
    __shared__ float sv[1024];
    __shared__ float red[8];
    int g = blockIdx.x;
    int s = gstart[g], n = gstart[g+1] - s;
    int tid = threadIdx.x;
    bool fit = (n <= 1024);
    float lmn = 3.4e38f, lmx = -3.4e38f;
    for (int i = tid; i < n; i += 256){
        float v = vb ? va[s+i] + vb[s+i] : va[s+i];
        if (fit) sv[i] = v;
        lmn = fminf(lmn, v); lmx = fmaxf(lmx, v);
    }
    float lo, hi;
    block_minmax(lmn, lmx, red, lo, hi);
    float inv = 1.f/(hi - lo + 1e-8f);
    if (!chain){
        for (int i = tid; i < n; i += 256){
            float v = fit ? sv[i] : (vb ? va[s+i] + vb[s+i] : va[s+i]);
            out[s+i] = (v - lo)*inv;
        }
        return;
    }
    lmn = 3.4e38f; lmx = -3.4e38f;
    for (int i = tid; i < n; i += 256){
        float v = fit ? sv[i] : va[s+i];
        float t = (v - lo)*inv;
        if (t < 0.1f) t = 0.f;
        if (fit) sv[i] = t;
        lmn = fminf(lmn, t); lmx = fmaxf(lmx, t);
    }
    float lo2, hi2;
    block_minmax(lmn, lmx, red, lo2, hi2);
    float inv2 = 1.f/(hi2 - lo2 + 1e-8f);
    for (int i = tid; i < n; i += 256){
        float t;
        if (fit) t = sv[i];
        else { float v = va[s+i]; t = (v - lo)*inv; if (t < 0.1f) t = 0.f; }
        out[s+i] = (t - lo2)*inv2;
    }
}

// Fold imp_proj into init_W: W0 is (FT+1) x HD, b0 = init_b + pb @ init_W[FT:]
__global__ void k_fold_init(const float* __restrict__ pW, const float* __restrict__ pb,
                            const float* __restrict__ iW, const float* __restrict__ ib,
                            float* __restrict__ W0, float* __restrict__ b0){
    int j = threadIdx.x;
    for (int k = 0; k < FT; ++k) W0[k*HD + j] = iW[k*HD + j];
    float w2 = 0.f, b2 = 0.f;
    for (int k = 0; k < HD; ++k){
        float w = iW[(FT + k)*HD + j];
        w2 += pW[k]*w;
        b2 += pb[k]*w;
    }
    W0[FT*HD + j] = w2;
    b0[j] = ib[j] + b2;
}

// ---------- node GEMM: out(N,128) = [A | B | scal] @ W + bias ----------
// mode 0: plain.  mode 1: gate epilogue (A==conv): out = sig(z)*conv + (1-sig(z))*hprev
#define NT 16
__global__ __launch_bounds__(128) void k_gemm(
    const float* __restrict__ A, int Ka,
    const float* __restrict__ B, int Kb,
    const float* __restrict__ scal,
    const float* __restrict__ W,
    const float* __restrict__ bias,
    const float* __restrict__ hprev,
    float* __restrict__ out,
    int mode)
{
    __shared__ float lds[NT][256];
    __shared__ float scs[NT];
    const int Kt = Ka + Kb;
    const int base = blockIdx.x * NT;     // NN % NT == 0, no tail
    const int tid = threadIdx.x;
    for (int t = 0; t < NT; ++t){
        int node = base + t;
        for (int k = tid; k < Kt; k += 128){
            float v;
            if (k < Ka) v = A[(size_t)node*Ka + k];
            else        v = B[(size_t)node*Kb + (k - Ka)];
            lds[t][k] = v;
        }
    }
    if (tid < NT) scs[tid] = scal ? scal[base + tid] : 0.f;
    __syncthreads();

    float acc[NT];
    #pragma unroll
    for (int t = 0; t < NT; ++t) acc[t] = 0.f;
    const int j = tid;
    for (int k = 0; k < Kt; ++k){
        float w = W[k*HD + j];
        #pragma unroll
        for (int t = 0; t < NT; ++t) acc[t] = fmaf(lds[t][k], w, acc[t]);
    }
    if (scal){
        float w = W[Kt*HD + j];
        #pragma unroll
        for (int t = 0; t < NT; ++t) acc[t] = fmaf(scs[t], w, acc[t]);
    }
    float bj = bias ? bias[j] : 0.f;
    for (int t = 0; t < NT; ++t){
        int node = base + t;
        float z = acc[t] + bj;
        if (mode == 0){
            out[(size_t)node*HD + j] = z;
        } else {
            float g = 1.f/(1.f + expf(-z));
            float c = lds[t][j];                         // conv value (A==conv, Ka==HD)
            float hp = hprev[(size_t)node*HD + j];
            out[(size_t)node*HD + j] = g*c + (1.f - g)*hp;
        }
    }
}

// ---------- CSR build (by dst) ----------
__global__ void k_deg(const int* __restrict__ dst, int* deg){
    int e = blockIdx.x*blockDim.x + threadIdx.x;
    if (e < NE) atomicAdd(&deg[dst[e]], 1);
}

__global__ void k_scan(const int* __restrict__ deg, int* __restrict__ rowstart){
    __shared__ int buf[1024];
    __shared__ int carry;
    if (threadIdx.x == 0) carry = 0;
    __syncthreads();
    for (int base = 0; base < NN; base += 1024){
        int i = base + (int)threadIdx.x;
        int v = (i < NN) ? deg[i] : 0;
        buf[threadIdx.x] = v;
        __syncthreads();
        for (int off = 1; off < 1024; off <<= 1){
            int t = (threadIdx.x >= (unsigned)off) ? buf[threadIdx.x - off] : 0;
            __syncthreads();
            buf[threadIdx.x] += t;
            __syncthreads();
        }
        if (i < NN) rowstart[i] = carry + buf[threadIdx.x] - v;   // exclusive
        __syncthreads();
        if (threadIdx.x == 0) carry += buf[1023];
        __syncthreads();
    }
    if (threadIdx.x == 0) rowstart[NN] = carry;
}

__global__ void k_copy_int(const int* __restrict__ a, int* __restrict__ b, int n){
    int i = blockIdx.x*blockDim.x + threadIdx.x;
    if (i < n) b[i] = a[i];
}

__global__ void k_fill(const int* __restrict__ src, const int* __restrict__ dst,
                       int* cursor, int* __restrict__ csr){
    int e = blockIdx.x*blockDim.x + threadIdx.x;
    if (e < NE){
        int d = dst[e];
        int p = atomicAdd(&cursor[d], 1);
        csr[p] = src[e];
    }
}

__global__ void k_aggregate(const float* __restrict__ hm, const int* __restrict__ rowstart,
                            const int* __restrict__ csr, float* __restrict__ aggr){
    int node = blockIdx.x*2 + (threadIdx.x >> 7);
    int j = threadIdx.x & 127;
    if (node >= NN) return;
    float acc = 0.f;
    int e0 = rowstart[node], e1 = rowstart[node + 1];
    for (int e = e0; e < e1; ++e){
        int s = csr[e];
        acc += hm[(size_t)s*HD + j];
    }
    aggr[(size_t)node*HD + j] = acc;
}

// prop = out @ prop_W + prop_b ; impnew = 0.9*imp + 0.1*prop
__global__ void k_prop_imp(const float* __restrict__ outv, const float* __restrict__ pW,
                           const float* __restrict__ pb, const float* __restrict__ imp,
                           float* __restrict__ impnew){
    int gid = blockIdx.x*blockDim.x + threadIdx.x;
    int wave = gid >> 6;
    int lane = threadIdx.x & 63;
    if (wave >= NN) return;
    float a = outv[(size_t)wave*HD + lane]*pW[lane]
            + outv[(size_t)wave*HD + 64 + lane]*pW[64 + lane];
    for (int off = 32; off > 0; off >>= 1) a += __shfl_down(a, off);
    if (lane == 0) impnew[wave] = 0.9f*imp[wave] + 0.1f*(a + pb[0]);
}

// ---------- per-graph column reductions (batch is contiguous runs) ----------
#define CHUNK 256
__global__ void k_colsum(const float* __restrict__ v, const int* __restrict__ batch,
                         float* __restrict__ sums){
    int j = threadIdx.x;
    int start = blockIdx.x * CHUNK;
    if (start >= NN) return;
    int end = min(start + CHUNK, NN);
    int curg = batch[start];
    float acc = 0.f;
    for (int i = start; i < end; ++i){
        int g = batch[i];
        if (g != curg){ atomicAdd(&sums[curg*HD + j], acc); acc = 0.f; curg = g; }
        acc += v[(size_t)i*HD + j];
    }
    atomicAdd(&sums[curg*HD + j], acc);
}

__global__ void k_colvar(const float* __restrict__ v, const int* __restrict__ batch,
                         const float* __restrict__ sums, const int* __restrict__ counts,
                         const float* __restrict__ na, float* __restrict__ vsums){
    int j = threadIdx.x;
    int start = blockIdx.x * CHUNK;
    if (start >= NN) return;
    int end = min(start + CHUNK, NN);
    float aj = na[j];
    int curg = batch[start];
    float m = aj * sums[curg*HD + j] / (float)counts[curg];
    float acc = 0.f;
    for (int i = start; i < end; ++i){
        int g = batch[i];
        if (g != curg){
            atomicAdd(&vsums[curg*HD + j], acc); acc = 0.f; curg = g;
            m = aj * sums[curg*HD + j] / (float)counts[curg];
        }
        float t = v[(size_t)i*HD + j] - m;
        acc += t*t;
    }
    atomicAdd(&vsums[curg*HD + j], acc);
}

__global__ void k_norm_fin(const float* __restrict__ v, const int* __restrict__ batch,
                           const float* __restrict__ sums, const float* __restrict__ vsums,
                           const int* __restrict__ counts,
                           const float* __restrict__ nw, const float* __restrict__ nb,
                           const float* __restrict__ na, float* __restrict__ hout){
    int idx = blockIdx.x*blockDim.x + threadIdx.x;
    int i = idx >> 7, j = idx & 127;
    if (i >= NN) return;
    int g = batch[i];
    float cnt = (float)counts[g];
    float mean = sums[g*HD + j] / cnt;
    float var  = vsums[g*HD + j] / cnt;
    float t = v[(size_t)i*HD + j] - na[j]*mean;
    float r = nw[j]*t / sqrtf(var + 1e-5f) + nb[j];
    hout[(size_t)i*HD + j] = r > 0.f ? r : 0.f;
}

// logits[g] = (segsum h)[g] @ final_W / cnt[g] + final_b
__global__ void k_final_logits(const float* __restrict__ gsum, const int* __restrict__ counts,
                               const float* __restrict__ fW, const float* __restrict__ fb,
                               float* __restrict__ logits){
    int g = blockIdx.x, o = threadIdx.x;   // 64 blocks x 32 threads
    float acc = 0.f;
    for (int jj = 0; jj < HD; ++jj) acc += gsum[g*HD + jj]*fW[jj*32 + o];
    logits[g*32 + o] = acc/(float)counts[g] + fb[o];
}

extern "C" void kernel_launch(void* const* d_in, const int* in_sizes, int n_in,
                              void* d_out, int out_size, void* d_ws, size_t ws_size,
                              hipStream_t stream){
    const float* x    = (const float*)d_in[0];
    const float* imp0 = (const float*)d_in[2];
    const float* pW   = (const float*)d_in[3];
    const float* pb   = (const float*)d_in[4];
    const float* iW   = (const float*)d_in[5];
    const float* ib   = (const float*)d_in[6];
    const float* msgW = (const float*)d_in[7];
    const float* msgb = (const float*)d_in[8];
    const float* updW = (const float*)d_in[9];
    const float* updb = (const float*)d_in[10];
    const float* gWt  = (const float*)d_in[11];
    const float* gb   = (const float*)d_in[12];
    const float* prW  = (const float*)d_in[13];
    const float* prb  = (const float*)d_in[14];
    const float* nw   = (const float*)d_in[15];
    const float* nb   = (const float*)d_in[16];
    const float* na   = (const float*)d_in[17];
    const float* fW   = (const float*)d_in[18];
    const float* fb   = (const float*)d_in[19];
    const int* eidx   = (const int*)d_in[20];
    const int* batch  = (const int*)d_in[21];
    const int* esrc = eidx;
    const int* edst = eidx + NE;
    float* outp = (float*)d_out;

    char* w = (char*)d_ws;
    size_t off = 0;
    auto alloc = [&](size_t bytes)->char*{
        char* p = w + off;
        off += (bytes + 255) & ~(size_t)255;
        return p;
    };
    float* h     = (float*)alloc((size_t)NN*HD*4);
    float* bufA  = (float*)alloc((size_t)NN*HD*4);
    float* bufB  = (float*)alloc((size_t)NN*HD*4);
    float* ta    = (float*)alloc((size_t)NN*4);
    float* imp   = (float*)alloc((size_t)NN*4);
    float* W0    = (float*)alloc((size_t)(FT+1)*HD*4);
    float* b0    = (float*)alloc((size_t)HD*4);
    float* gsum  = (float*)alloc((size_t)NG*HD*4);
    float* gsum2 = (float*)alloc((size_t)NG*HD*4);
    int* gstart  = (int*)alloc((size_t)(NG+1)*4);
    int* counts  = (int*)alloc((size_t)NG*4);
    int* deg     = (int*)alloc((size_t)NN*4);
    int* rowst   = (int*)alloc((size_t)(NN+1)*4);
    int* cursor  = (int*)alloc((size_t)NN*4);
    int* csr     = (int*)alloc((size_t)NE*4);

    // graph boundaries + sizes (batch is sorted contiguous; zero atomics)
    k_gbounds<<<196, 256, 0, stream>>>(batch, gstart);
    k_counts_b<<<1, 64, 0, stream>>>(gstart, counts);

    // CSR by dst (once; reused for all 3 layers)
    hipMemsetAsync(deg, 0, NN*4, stream);
    k_deg<<<3125, 256, 0, stream>>>(edst, deg);
    k_scan<<<1, 1024, 0, stream>>>(deg, rowst);
    k_copy_int<<<196, 256, 0, stream>>>(rowst, cursor, NN);
    k_fill<<<3125, 256, 0, stream>>>(esrc, edst, cursor, csr);

    // importance = normalize(imp0)
    k_norm_graph<<<NG, 256, 0, stream>>>(imp0, nullptr, gstart, imp, 0);

    // h = [x, imp_emb] @ init_W + init_b  (imp_proj folded)
    k_fold_init<<<1, 128, 0, stream>>>(pW, pb, iW, ib, W0, b0);
    k_gemm<<<3125, 128, 0, stream>>>(x, FT, nullptr, 0, imp, W0, b0, nullptr, h, 0);

    for (int l = 0; l < NLAYERS; ++l){
        const float* mWl = msgW + (size_t)l*HD*HD;
        const float* uWl = updW + (size_t)l*2*HD*HD;
        const float* gWl = gWt  + (size_t)l*(HD+1)*HD;
        // hm = h @ msg_W + msg_b  (aggr of msg == scatter-sum of hm[src])
        k_gemm<<<3125, 128, 0, stream>>>(h, HD, nullptr, 0, nullptr, mWl, msgb + l*HD, nullptr, bufA, 0);
        k_aggregate<<<25000, 256, 0, stream>>>(bufA, rowst, csr, bufB);
        // conv = [h, aggr] @ upd_W + upd_b
        k_gemm<<<3125, 128, 0, stream>>>(h, HD, bufB, HD, nullptr, uWl, updb + l*HD, nullptr, bufB, 0);
        // gate + out fused:  out = sig([conv, imp]@gate_W + gate_b)*conv + (1-..)*h
        k_gemm<<<3125, 128, 0, stream>>>(bufB, HD, nullptr, 0, imp, gWl, gb + l*HD, h, bufB, 1);
        // prop + importance decay
        k_prop_imp<<<12500, 256, 0, stream>>>(bufB, prW + (size_t)l*HD, prb + l, imp, ta);
        // imp = normalize(normalize(ta) thresholded)  — single fused kernel
        k_norm_graph<<<NG, 256, 0, stream>>>(ta, nullptr, gstart, imp, 1);
        // graph norm -> h = relu(...)
        hipMemsetAsync(gsum,  0, NG*HD*4, stream);
        hipMemsetAsync(gsum2, 0, NG*HD*4, stream);
        k_colsum<<<196, 128, 0, stream>>>(bufB, batch, gsum);
        k_colvar<<<196, 128, 0, stream>>>(bufB, batch, gsum, counts, na + l*HD, gsum2);
        k_norm_fin<<<25000, 256, 0, stream>>>(bufB, batch, gsum, gsum2, counts,
                                              nw + l*HD, nb + l*HD, na + l*HD, h);
    }

    // logits
    hipMemsetAsync(gsum, 0, NG*HD*4, stream);
    k_colsum<<<196, 128, 0, stream>>>(h, batch, gsum);
    k_final_logits<<<64, 32, 0, stream>>>(gsum, counts, fW, fb, outp);

    // final_importance = normalize(imp0 + importance)
    k_norm_graph<<<NG, 256, 0, stream>>>(imp0, imp, gstart, outp + NG*32, 0);
}

// Round 3
// 862.401 us; speedup vs baseline: 5.2478x; 2.3288x over previous
//
#include <hip/hip_runtime.h>
#include <cstdint>

#define NN 50000
#define NE 800000
#define NG 64
#define HD 128
#define FT 64
#define NLAYERS 3
#define NT 16

// ---------- graph boundaries (batch is sorted contiguous runs) ----------
__global__ void k_gbounds(const int* __restrict__ batch, int* __restrict__ gstart){
    int i = blockIdx.x*blockDim.x + threadIdx.x;
    if (i >= NN) return;
    int g = batch[i];
    if (i == 0){ for (int q = 0; q <= g; ++q) gstart[q] = 0; }
    else { int gp = batch[i-1]; for (int q = gp+1; q <= g; ++q) gstart[q] = i; }
    if (i == NN-1){ for (int q = g+1; q <= NG; ++q) gstart[q] = NN; }
}

// ---------- block-wide min/max reduce helper (256 threads = 4 waves) ----------
__device__ __forceinline__ void block_minmax(float lmn, float lmx, float* red,
                                             float& omn, float& omx){
    #pragma unroll
    for (int off = 32; off > 0; off >>= 1){
        lmn = fminf(lmn, __shfl_xor(lmn, off));
        lmx = fmaxf(lmx, __shfl_xor(lmx, off));
    }
    int wave = threadIdx.x >> 6;
    if ((threadIdx.x & 63) == 0){ red[wave] = lmn; red[4+wave] = lmx; }
    __syncthreads();
    omn = fminf(fminf(red[0], red[1]), fminf(red[2], red[3]));
    omx = fmaxf(fmaxf(red[4], red[5]), fmaxf(red[6], red[7]));
    __syncthreads();
}

// ---------- fused per-graph normalize (one block per graph, zero atomics) ----
__global__ __launch_bounds__(256) void k_norm_graph(
    const float* __restrict__ va, const float* __restrict__ vb,
    const int* __restrict__ gstart, float* __restrict__ out, int chain)
{
    __shared__ float sv[1024];
    __shared__ float red[8];
    int g = blockIdx.x;
    int s = gstart[g], n = gstart[g+1] - s;
    int tid = threadIdx.x;
    bool fit = (n <= 1024);
    float lmn = 3.4e38f, lmx = -3.4e38f;
    for (int i = tid; i < n; i += 256){
        float v = vb ? va[s+i] + vb[s+i] : va[s+i];
        if (fit) sv[i] = v;
        lmn = fminf(lmn, v); lmx = fmaxf(lmx, v);
    }
    float lo, hi;
    block_minmax(lmn, lmx, red, lo, hi);
    float inv = 1.f/(hi - lo + 1e-8f);
    if (!chain){
        for (int i = tid; i < n; i += 256){
            float v = fit ? sv[i] : (vb ? va[s+i] + vb[s+i] : va[s+i]);
            out[s+i] = (v - lo)*inv;
        }
        return;
    }
    lmn = 3.4e38f; lmx = -3.4e38f;
    for (int i = tid; i < n; i += 256){
        float v = fit ? sv[i] : va[s+i];
        float t = (v - lo)*inv;
        if (t < 0.1f) t = 0.f;
        if (fit) sv[i] = t;
        lmn = fminf(lmn, t); lmx = fmaxf(lmx, t);
    }
    float lo2, hi2;
    block_minmax(lmn, lmx, red, lo2, hi2);
    float inv2 = 1.f/(hi2 - lo2 + 1e-8f);
    for (int i = tid; i < n; i += 256){
        float t;
        if (fit) t = sv[i];
        else { float v = va[s+i]; t = (v - lo)*inv; if (t < 0.1f) t = 0.f; }
        out[s+i] = (t - lo2)*inv2;
    }
}

// Fold imp_proj into init_W: W0 is (FT+1) x HD, b0 = init_b + pb @ init_W[FT:]
__global__ void k_fold_init(const float* __restrict__ pW, const float* __restrict__ pb,
                            const float* __restrict__ iW, const float* __restrict__ ib,
                            float* __restrict__ W0, float* __restrict__ b0){
    int j = threadIdx.x;
    for (int k = 0; k < FT; ++k) W0[k*HD + j] = iW[k*HD + j];
    float w2 = 0.f, b2 = 0.f;
    for (int k = 0; k < HD; ++k){
        float w = iW[(FT + k)*HD + j];
        w2 += pW[k]*w;
        b2 += pb[k]*w;
    }
    W0[FT*HD + j] = w2;
    b0[j] = ib[j] + b2;
}

// Wc = msg_W @ uW_bot (128x128), bc = msg_b @ uW_bot (128). grid 129 x 128.
__global__ void k_fold_layer(const float* __restrict__ mW, const float* __restrict__ uWbot,
                             const float* __restrict__ msgb,
                             float* __restrict__ Wc, float* __restrict__ bc){
    int j = threadIdx.x;
    int r = blockIdx.x;
    const float* rowp = (r < HD) ? (mW + (size_t)r*HD) : msgb;
    float acc = 0.f;
    for (int k = 0; k < HD; ++k) acc = fmaf(rowp[k], uWbot[(size_t)k*HD + j], acc);
    if (r < HD) Wc[(size_t)r*HD + j] = acc; else bc[j] = acc;
}

// ---------- init GEMM: h = x @ W0[0:64] + imp*W0[64] + b0 ----------
__global__ __launch_bounds__(128) void k_init(
    const float* __restrict__ x, const float* __restrict__ imp,
    const float* __restrict__ W0, const float* __restrict__ b0,
    float* __restrict__ h)
{
    __shared__ float lds[NT][FT];
    __shared__ float scs[NT];
    int base = blockIdx.x*NT, tid = threadIdx.x;
    #pragma unroll
    for (int i = 0; i < 2; ++i){
        int fidx = i*128 + tid;          // 16 rows x 16 float4
        int t = fidx >> 4, c = fidx & 15;
        *(float4*)&lds[t][c*4] = *(const float4*)&x[(size_t)(base+t)*FT + c*4];
    }
    if (tid < NT) scs[tid] = imp[base+tid];
    __syncthreads();
    const int j = tid;
    float wlast = W0[FT*HD + j], b = b0[j];
    float acc[NT];
    #pragma unroll
    for (int t = 0; t < NT; ++t) acc[t] = fmaf(scs[t], wlast, b);
    for (int k4 = 0; k4 < 16; ++k4){
        const float* wp = W0 + (k4*4)*HD + j;
        float w0 = wp[0], w1 = wp[HD], w2 = wp[2*HD], w3 = wp[3*HD];
        #pragma unroll
        for (int t = 0; t < NT; ++t){
            const float4 a = *(const float4*)&lds[t][k4*4];
            acc[t] = fmaf(a.x,w0, fmaf(a.y,w1, fmaf(a.z,w2, fmaf(a.w,w3, acc[t]))));
        }
    }
    #pragma unroll
    for (int t = 0; t < NT; ++t) h[(size_t)(base+t)*HD + j] = acc[t];
}

// ---------- per-layer mega kernel ----------
// conv = h@uW_top + aggr@Wc + deg*bc + ub ; z = conv@gW_top + imp*gW[128] + gb
// out  = sig(z)*conv + (1-sig(z))*h ; ta = 0.9*imp + 0.1*(out.prW + prb)
__global__ __launch_bounds__(128) void k_layer(
    const float* __restrict__ h, const float* __restrict__ aggr,
    const float* __restrict__ imp, const int* __restrict__ deg,
    const float* __restrict__ uW, const float* __restrict__ Wc,
    const float* __restrict__ bc, const float* __restrict__ ub,
    const float* __restrict__ gW, const float* __restrict__ gb,
    const float* __restrict__ prW, const float* __restrict__ prb,
    float* __restrict__ outbuf, float* __restrict__ ta)
{
    __shared__ float lds[NT][256];
    __shared__ float clds[NT][HD];
    __shared__ float scs[NT];
    __shared__ float dgs[NT];
    __shared__ float red[2][NT];
    const int base = blockIdx.x*NT, tid = threadIdx.x;

    // stage [h | aggr]: 16 rows x 64 float4
    #pragma unroll
    for (int i = 0; i < 8; ++i){
        int fidx = i*128 + tid;
        int t = fidx >> 6, c = fidx & 63;
        const float* srcp = (c < 32) ? &h[(size_t)(base+t)*HD + c*4]
                                     : &aggr[(size_t)(base+t)*HD + (c-32)*4];
        *(float4*)&lds[t][c*4] = *(const float4*)srcp;
    }
    if (tid < NT) scs[tid] = imp[base+tid];
    else if (tid < 2*NT) dgs[tid-NT] = (float)deg[base+tid-NT];
    __syncthreads();

    const int j = tid;
    float bcj = bc[j], ubj = ub[j];
    float acc[NT];
    #pragma unroll
    for (int t = 0; t < NT; ++t) acc[t] = fmaf(dgs[t], bcj, ubj);
    for (int k4 = 0; k4 < 32; ++k4){
        const float* wp = uW + (k4*4)*HD + j;
        float w0 = wp[0], w1 = wp[HD], w2 = wp[2*HD], w3 = wp[3*HD];
        #pragma unroll
        for (int t = 0; t < NT; ++t){
            const float4 a = *(const float4*)&lds[t][k4*4];
            acc[t] = fmaf(a.x,w0, fmaf(a.y,w1, fmaf(a.z,w2, fmaf(a.w,w3, acc[t]))));
        }
    }
    for (int k4 = 0; k4 < 32; ++k4){
        const float* wp = Wc + (k4*4)*HD + j;
        float w0 = wp[0], w1 = wp[HD], w2 = wp[2*HD], w3 = wp[3*HD];
        #pragma unroll
        for (int t = 0; t < NT; ++t){
            const float4 a = *(const float4*)&lds[t][128 + k4*4];
            acc[t] = fmaf(a.x,w0, fmaf(a.y,w1, fmaf(a.z,w2, fmaf(a.w,w3, acc[t]))));
        }
    }
    #pragma unroll
    for (int t = 0; t < NT; ++t) clds[t][j] = acc[t];
    __syncthreads();

    // gate GEMM over conv
    float gwl = gW[128*HD + j], gbj = gb[j];
    float z[NT];
    #pragma unroll
    for (int t = 0; t < NT; ++t) z[t] = fmaf(scs[t], gwl, gbj);
    for (int k4 = 0; k4 < 32; ++k4){
        const float* wp = gW + (k4*4)*HD + j;
        float w0 = wp[0], w1 = wp[HD], w2 = wp[2*HD], w3 = wp[3*HD];
        #pragma unroll
        for (int t = 0; t < NT; ++t){
            const float4 a = *(const float4*)&clds[t][k4*4];
            z[t] = fmaf(a.x,w0, fmaf(a.y,w1, fmaf(a.z,w2, fmaf(a.w,w3, z[t]))));
        }
    }

    // epilogue: gate mix, store out, prop partials
    float prwj = prW[j];
    float psum[NT];
    #pragma unroll
    for (int t = 0; t < NT; ++t){
        float g = 1.f/(1.f + expf(-z[t]));
        float cv = clds[t][j];
        float hv = lds[t][j];
        float o = g*cv + (1.f - g)*hv;
        outbuf[(size_t)(base+t)*HD + j] = o;
        psum[t] = o*prwj;
    }
    int wv = tid >> 6, lane = tid & 63;
    #pragma unroll
    for (int t = 0; t < NT; ++t){
        float v = psum[t];
        #pragma unroll
        for (int off = 32; off > 0; off >>= 1) v += __shfl_xor(v, off);
        if (lane == 0) red[wv][t] = v;
    }
    __syncthreads();
    if (tid < NT)
        ta[base+tid] = 0.9f*scs[tid] + 0.1f*(red[0][tid] + red[1][tid] + prb[0]);
}

// ---------- CSR build (by dst) ----------
__global__ void k_deg(const int* __restrict__ dst, int* deg){
    int e = blockIdx.x*blockDim.x + threadIdx.x;
    if (e < NE) atomicAdd(&deg[dst[e]], 1);
}

__global__ __launch_bounds__(1024) void k_scan(const int* __restrict__ deg,
                                               int* __restrict__ rowstart){
    __shared__ int wtot[16];
    __shared__ int woff[16];
    __shared__ int carry;
    int tid = threadIdx.x, lane = tid & 63, wv = tid >> 6;
    if (tid == 0) carry = 0;
    __syncthreads();
    for (int base = 0; base < NN; base += 1024){
        int i = base + tid;
        int v = (i < NN) ? deg[i] : 0;
        int x = v;
        #pragma unroll
        for (int off = 1; off < 64; off <<= 1){
            int y = __shfl_up(x, off);
            if (lane >= off) x += y;
        }
        if (lane == 63) wtot[wv] = x;
        __syncthreads();
        if (tid == 0){
            int a = carry;
            for (int w2 = 0; w2 < 16; ++w2){ woff[w2] = a; a += wtot[w2]; }
            carry = a;
        }
        __syncthreads();
        if (i < NN) rowstart[i] = woff[wv] + x - v;   // exclusive
    }
    __syncthreads();
    if (tid == 0) rowstart[NN] = carry;
}

__global__ void k_copy_int(const int* __restrict__ a, int* __restrict__ b, int n){
    int i = blockIdx.x*blockDim.x + threadIdx.x;
    if (i < n) b[i] = a[i];
}

__global__ void k_fill(const int* __restrict__ src, const int* __restrict__ dst,
                       int* cursor, int* __restrict__ csr){
    int e = blockIdx.x*blockDim.x + threadIdx.x;
    if (e < NE){
        int d = dst[e];
        int p = atomicAdd(&cursor[d], 1);
        csr[p] = src[e];
    }
}

// aggr[node] = sum over in-edges of hm[src], float4 lanes, 2-edge unroll
__global__ __launch_bounds__(256) void k_aggregate(
    const float* __restrict__ hm, const int* __restrict__ rowstart,
    const int* __restrict__ csr, float* __restrict__ aggr)
{
    int node = blockIdx.x*8 + (threadIdx.x >> 5);
    int lane = threadIdx.x & 31;
    float4 acc; acc.x = acc.y = acc.z = acc.w = 0.f;
    int e0 = rowstart[node], e1 = rowstart[node+1];
    int e = e0;
    for (; e + 1 < e1; e += 2){
        int s0 = csr[e], s1 = csr[e+1];
        const float4 v0 = *(const float4*)&hm[(size_t)s0*HD + lane*4];
        const float4 v1 = *(const float4*)&hm[(size_t)s1*HD + lane*4];
        acc.x += v0.x + v1.x; acc.y += v0.y + v1.y;
        acc.z += v0.z + v1.z; acc.w += v0.w + v1.w;
    }
    if (e < e1){
        int s0 = csr[e];
        const float4 v0 = *(const float4*)&hm[(size_t)s0*HD + lane*4];
        acc.x += v0.x; acc.y += v0.y; acc.z += v0.z; acc.w += v0.w;
    }
    *(float4*)&aggr[(size_t)node*HD + lane*4] = acc;
}

// ---------- fused graph-norm: stats (sum,sumsq) + normalize + relu ----------
__global__ __launch_bounds__(1024) void k_graphnorm(
    const float* __restrict__ v, const int* __restrict__ gstart,
    const float* __restrict__ nw, const float* __restrict__ nb,
    const float* __restrict__ na, float* __restrict__ hout)
{
    __shared__ float4 rs1[32][32];
    __shared__ float4 rs2[32][32];
    __shared__ float amv[HD], scv[HD], nbv[HD];
    int g = blockIdx.x;
    int s = gstart[g], n = gstart[g+1] - s;
    int c4 = threadIdx.x & 31, rg = threadIdx.x >> 5;
    float4 s1, s2; s1.x=s1.y=s1.z=s1.w=0.f; s2.x=s2.y=s2.z=s2.w=0.f;
    for (int i = rg; i < n; i += 32){
        const float4 vv = *(const float4*)&v[(size_t)(s+i)*HD + c4*4];
        s1.x += vv.x; s1.y += vv.y; s1.z += vv.z; s1.w += vv.w;
        s2.x += vv.x*vv.x; s2.y += vv.y*vv.y; s2.z += vv.z*vv.z; s2.w += vv.w*vv.w;
    }
    rs1[rg][c4] = s1; rs2[rg][c4] = s2;
    __syncthreads();
    if (threadIdx.x < 32){
        int cc = threadIdx.x;
        float4 t1, t2; t1.x=t1.y=t1.z=t1.w=0.f; t2.x=t2.y=t2.z=t2.w=0.f;
        for (int r = 0; r < 32; ++r){
            float4 a = rs1[r][cc]; float4 b = rs2[r][cc];
            t1.x += a.x; t1.y += a.y; t1.z += a.z; t1.w += a.w;
            t2.x += b.x; t2.y += b.y; t2.z += b.z; t2.w += b.w;
        }
        float fn = (float)n;
        float S1[4] = {t1.x,t1.y,t1.z,t1.w};
        float S2[4] = {t2.x,t2.y,t2.z,t2.w};
        #pragma unroll
        for (int e = 0; e < 4; ++e){
            int j = cc*4 + e;
            float m = S1[e]/fn;
            float aj = na[j];
            float var = S2[e]/fn - (2.f*aj - aj*aj)*m*m;
            float stdv = sqrtf(var + 1e-5f);
            amv[j] = aj*m;
            scv[j] = nw[j]/stdv;
            nbv[j] = nb[j];
        }
    }
    __syncthreads();
    const float4 am4 = *(const float4*)&amv[c4*4];
    const float4 sc4 = *(const float4*)&scv[c4*4];
    const float4 nb4 = *(const float4*)&nbv[c4*4];
    for (int i = rg; i < n; i += 32){
        const float4 vv = *(const float4*)&v[(size_t)(s+i)*HD + c4*4];
        float4 r;
        r.x = fmaxf((vv.x - am4.x)*sc4.x + nb4.x, 0.f);
        r.y = fmaxf((vv.y - am4.y)*sc4.y + nb4.y, 0.f);
        r.z = fmaxf((vv.z - am4.z)*sc4.z + nb4.z, 0.f);
        r.w = fmaxf((vv.w - am4.w)*sc4.w + nb4.w, 0.f);
        *(float4*)&hout[(size_t)(s+i)*HD + c4*4] = r;
    }
}

// ---------- fused final: per-graph column-sum + tiny GEMM to logits ----------
__global__ __launch_bounds__(1024) void k_logits(
    const float* __restrict__ h, const int* __restrict__ gstart,
    const float* __restrict__ fW, const float* __restrict__ fb,
    float* __restrict__ outp)
{
    __shared__ float4 rs1[32][32];
    __shared__ float gsum[HD];
    int g = blockIdx.x;
    int s = gstart[g], n = gstart[g+1] - s;
    int c4 = threadIdx.x & 31, rg = threadIdx.x >> 5;
    float4 s1; s1.x=s1.y=s1.z=s1.w=0.f;
    for (int i = rg; i < n; i += 32){
        const float4 vv = *(const float4*)&h[(size_t)(s+i)*HD + c4*4];
        s1.x += vv.x; s1.y += vv.y; s1.z += vv.z; s1.w += vv.w;
    }
    rs1[rg][c4] = s1;
    __syncthreads();
    if (threadIdx.x < 32){
        int cc = threadIdx.x;
        float4 t1; t1.x=t1.y=t1.z=t1.w=0.f;
        for (int r = 0; r < 32; ++r){
            float4 a = rs1[r][cc];
            t1.x += a.x; t1.y += a.y; t1.z += a.z; t1.w += a.w;
        }
        gsum[cc*4+0] = t1.x; gsum[cc*4+1] = t1.y;
        gsum[cc*4+2] = t1.z; gsum[cc*4+3] = t1.w;
    }
    __syncthreads();
    if (threadIdx.x < 32){
        int o = threadIdx.x;
        float acc = 0.f;
        for (int k = 0; k < HD; ++k) acc = fmaf(gsum[k], fW[k*32 + o], acc);
        outp[g*32 + o] = acc/(float)n + fb[o];
    }
}

extern "C" void kernel_launch(void* const* d_in, const int* in_sizes, int n_in,
                              void* d_out, int out_size, void* d_ws, size_t ws_size,
                              hipStream_t stream){
    const float* x    = (const float*)d_in[0];
    const float* imp0 = (const float*)d_in[2];
    const float* pW   = (const float*)d_in[3];
    const float* pb   = (const float*)d_in[4];
    const float* iW   = (const float*)d_in[5];
    const float* ib   = (const float*)d_in[6];
    const float* msgW = (const float*)d_in[7];
    const float* msgb = (const float*)d_in[8];
    const float* updW = (const float*)d_in[9];
    const float* updb = (const float*)d_in[10];
    const float* gWt  = (const float*)d_in[11];
    const float* gb   = (const float*)d_in[12];
    const float* prW  = (const float*)d_in[13];
    const float* prb  = (const float*)d_in[14];
    const float* nw   = (const float*)d_in[15];
    const float* nb   = (const float*)d_in[16];
    const float* na   = (const float*)d_in[17];
    const float* fW   = (const float*)d_in[18];
    const float* fb   = (const float*)d_in[19];
    const int* eidx   = (const int*)d_in[20];
    const int* batch  = (const int*)d_in[21];
    const int* esrc = eidx;
    const int* edst = eidx + NE;
    float* outp = (float*)d_out;

    char* w = (char*)d_ws;
    size_t off = 0;
    auto alloc = [&](size_t bytes)->char*{
        char* p = w + off;
        off += (bytes + 255) & ~(size_t)255;
        return p;
    };
    float* h     = (float*)alloc((size_t)NN*HD*4);
    float* aggB  = (float*)alloc((size_t)NN*HD*4);
    float* outA  = (float*)alloc((size_t)NN*HD*4);
    float* ta    = (float*)alloc((size_t)NN*4);
    float* imp   = (float*)alloc((size_t)NN*4);
    float* W0    = (float*)alloc((size_t)(FT+1)*HD*4);
    float* b0    = (float*)alloc((size_t)HD*4);
    float* Wc    = (float*)alloc((size_t)NLAYERS*HD*HD*4);
    float* bc    = (float*)alloc((size_t)NLAYERS*HD*4);
    int* gstart  = (int*)alloc((size_t)(NG+1)*4);
    int* deg     = (int*)alloc((size_t)NN*4);
    int* rowst   = (int*)alloc((size_t)(NN+1)*4);
    int* cursor  = (int*)alloc((size_t)NN*4);
    int* csr     = (int*)alloc((size_t)NE*4);

    // graph boundaries
    k_gbounds<<<196, 256, 0, stream>>>(batch, gstart);

    // CSR by dst
    hipMemsetAsync(deg, 0, NN*4, stream);
    k_deg<<<3125, 256, 0, stream>>>(edst, deg);
    k_scan<<<1, 1024, 0, stream>>>(deg, rowst);
    k_copy_int<<<196, 256, 0, stream>>>(rowst, cursor, NN);
    k_fill<<<3125, 256, 0, stream>>>(esrc, edst, cursor, csr);

    // weight folds
    k_fold_init<<<1, 128, 0, stream>>>(pW, pb, iW, ib, W0, b0);
    for (int l = 0; l < NLAYERS; ++l){
        k_fold_layer<<<129, 128, 0, stream>>>(
            msgW + (size_t)l*HD*HD, updW + (size_t)l*2*HD*HD + (size_t)HD*HD,
            msgb + (size_t)l*HD, Wc + (size_t)l*HD*HD, bc + (size_t)l*HD);
    }

    // importance = normalize(imp0); h = init GEMM
    k_norm_graph<<<NG, 256, 0, stream>>>(imp0, nullptr, gstart, imp, 0);
    k_init<<<3125, 128, 0, stream>>>(x, imp, W0, b0, h);

    for (int l = 0; l < NLAYERS; ++l){
        k_aggregate<<<6250, 256, 0, stream>>>(h, rowst, csr, aggB);
        k_layer<<<3125, 128, 0, stream>>>(
            h, aggB, imp, deg,
            updW + (size_t)l*2*HD*HD, Wc + (size_t)l*HD*HD, bc + (size_t)l*HD,
            updb + (size_t)l*HD, gWt + (size_t)l*(HD+1)*HD, gb + (size_t)l*HD,
            prW + (size_t)l*HD, prb + l, outA, ta);
        k_norm_graph<<<NG, 256, 0, stream>>>(ta, nullptr, gstart, imp, 1);
        k_graphnorm<<<NG, 1024, 0, stream>>>(outA, gstart,
            nw + (size_t)l*HD, nb + (size_t)l*HD, na + (size_t)l*HD, h);
    }

    // logits + final importance
    k_logits<<<NG, 1024, 0, stream>>>(h, gstart, fW, fb, outp);
    k_norm_graph<<<NG, 256, 0, stream>>>(imp0, imp, gstart, outp + NG*32, 0);
}

// Round 4
// 732.526 us; speedup vs baseline: 6.1782x; 1.1773x over previous
//
#include <hip/hip_runtime.h>
#include <cstdint>

#define NN 50000
#define NE 800000
#define NG 64
#define HD 128
#define FT 64
#define NLAYERS 3
#define MB 32
#define NBLK 1563   // ceil(NN/MB)

// ---------- graph boundaries (batch is sorted contiguous runs) ----------
__global__ void k_gbounds(const int* __restrict__ batch, int* __restrict__ gstart){
    int i = blockIdx.x*blockDim.x + threadIdx.x;
    if (i >= NN) return;
    int g = batch[i];
    if (i == 0){ for (int q = 0; q <= g; ++q) gstart[q] = 0; }
    else { int gp = batch[i-1]; for (int q = gp+1; q <= g; ++q) gstart[q] = i; }
    if (i == NN-1){ for (int q = g+1; q <= NG; ++q) gstart[q] = NN; }
}

// ---------- block-wide min/max reduce helper (256 threads = 4 waves) ----------
__device__ __forceinline__ void block_minmax(float lmn, float lmx, float* red,
                                             float& omn, float& omx){
    #pragma unroll
    for (int off = 32; off > 0; off >>= 1){
        lmn = fminf(lmn, __shfl_xor(lmn, off));
        lmx = fmaxf(lmx, __shfl_xor(lmx, off));
    }
    int wave = threadIdx.x >> 6;
    if ((threadIdx.x & 63) == 0){ red[wave] = lmn; red[4+wave] = lmx; }
    __syncthreads();
    omn = fminf(fminf(red[0], red[1]), fminf(red[2], red[3]));
    omx = fmaxf(fmaxf(red[4], red[5]), fmaxf(red[6], red[7]));
    __syncthreads();
}

// ---------- per-graph normalize (initial importance only) ----------
__global__ __launch_bounds__(256) void k_norm_graph(
    const float* __restrict__ va, const int* __restrict__ gstart,
    float* __restrict__ out)
{
    __shared__ float sv[1024];
    __shared__ float red[8];
    int g = blockIdx.x;
    int s = gstart[g], n = gstart[g+1] - s;
    int tid = threadIdx.x;
    float lmn = 3.4e38f, lmx = -3.4e38f;
    for (int i = tid; i < n; i += 256){
        float v = va[s+i];
        sv[i] = v;
        lmn = fminf(lmn, v); lmx = fmaxf(lmx, v);
    }
    float lo, hi;
    block_minmax(lmn, lmx, red, lo, hi);
    float inv = 1.f/(hi - lo + 1e-8f);
    for (int i = tid; i < n; i += 256) out[s+i] = (sv[i] - lo)*inv;
}

// Fold imp_proj into init_W: W0 is (FT+1) x HD, b0 = init_b + pb @ init_W[FT:]
__global__ void k_fold_init(const float* __restrict__ pW, const float* __restrict__ pb,
                            const float* __restrict__ iW, const float* __restrict__ ib,
                            float* __restrict__ W0, float* __restrict__ b0){
    int j = threadIdx.x;
    for (int k = 0; k < FT; ++k) W0[k*HD + j] = iW[k*HD + j];
    float w2 = 0.f, b2 = 0.f;
    for (int k = 0; k < HD; ++k){
        float w = iW[(FT + k)*HD + j];
        w2 += pW[k]*w;
        b2 += pb[k]*w;
    }
    W0[FT*HD + j] = w2;
    b0[j] = ib[j] + b2;
}

// Wf(256x128) = [uW_top ; msg_W @ uW_bot], bcv = msg_b @ uW_bot. grid 257x128.
__global__ void k_fold_layer(const float* __restrict__ mW, const float* __restrict__ uW,
                             const float* __restrict__ msgb,
                             float* __restrict__ Wf, float* __restrict__ bcv){
    int j = threadIdx.x;
    int r = blockIdx.x;
    if (r < HD){
        Wf[(size_t)r*HD + j] = uW[(size_t)r*HD + j];
    } else if (r < 2*HD){
        int rr = r - HD;
        const float* uWbot = uW + (size_t)HD*HD;
        float acc = 0.f;
        for (int k = 0; k < HD; ++k)
            acc = fmaf(mW[(size_t)rr*HD + k], uWbot[(size_t)k*HD + j], acc);
        Wf[(size_t)r*HD + j] = acc;
    } else {
        const float* uWbot = uW + (size_t)HD*HD;
        float acc = 0.f;
        for (int k = 0; k < HD; ++k)
            acc = fmaf(msgb[k], uWbot[(size_t)k*HD + j], acc);
        bcv[j] = acc;
    }
}

// ---------- init GEMM: h = x @ W0[0:64] + imp*W0[64] + b0 ----------
// 256 thr, 32 nodes/block, thread tile 8 rows x 2 cols
__global__ __launch_bounds__(256) void k_init(
    const float* __restrict__ x, const float* __restrict__ imp,
    const float* __restrict__ W0, const float* __restrict__ b0v,
    float* __restrict__ h)
{
    __shared__ float lds[MB][FT];
    __shared__ float scs[MB];
    int base = blockIdx.x*MB, tid = threadIdx.x;
    #pragma unroll
    for (int i = 0; i < 2; ++i){
        int fidx = i*256 + tid;
        int t = fidx >> 4, c = fidx & 15;
        float4 v = {0.f,0.f,0.f,0.f};
        if (base + t < NN) v = *(const float4*)&x[(size_t)(base+t)*FT + c*4];
        *(float4*)&lds[t][c*4] = v;
    }
    if (tid < MB) scs[tid] = (base+tid < NN) ? imp[base+tid] : 0.f;
    __syncthreads();

    const int rg = tid >> 6, c0 = (tid & 63)*2, r0 = rg*8;
    float accA[8], accB[8];
    {
        float wl0 = W0[(size_t)FT*HD + c0], wl1 = W0[(size_t)FT*HD + c0+1];
        float bb0 = b0v[c0], bb1 = b0v[c0+1];
        #pragma unroll
        for (int r = 0; r < 8; ++r){
            accA[r] = fmaf(scs[r0+r], wl0, bb0);
            accB[r] = fmaf(scs[r0+r], wl1, bb1);
        }
    }
    #pragma unroll 2
    for (int k4 = 0; k4 < 16; ++k4){
        float2 w0 = *(const float2*)&W0[(size_t)(k4*4+0)*HD + c0];
        float2 w1 = *(const float2*)&W0[(size_t)(k4*4+1)*HD + c0];
        float2 w2 = *(const float2*)&W0[(size_t)(k4*4+2)*HD + c0];
        float2 w3 = *(const float2*)&W0[(size_t)(k4*4+3)*HD + c0];
        #pragma unroll
        for (int r = 0; r < 8; ++r){
            const float4 a = *(const float4*)&lds[r0+r][k4*4];
            accA[r] = fmaf(a.x,w0.x, fmaf(a.y,w1.x, fmaf(a.z,w2.x, fmaf(a.w,w3.x, accA[r]))));
            accB[r] = fmaf(a.x,w0.y, fmaf(a.y,w1.y, fmaf(a.z,w2.y, fmaf(a.w,w3.y, accB[r]))));
        }
    }
    #pragma unroll
    for (int r = 0; r < 8; ++r)
        if (base + r0 + r < NN)
            *(float2*)&h[(size_t)(base+r0+r)*HD + c0] = make_float2(accA[r], accB[r]);
}

// ---------- per-layer mega kernel (reg-tiled) ----------
__global__ __launch_bounds__(256) void k_layer(
    const float* __restrict__ h, const float* __restrict__ aggr,
    const float* __restrict__ imp, const int* __restrict__ deg,
    const float* __restrict__ Wf, const float* __restrict__ bcv,
    const float* __restrict__ ub,
    const float* __restrict__ gW, const float* __restrict__ gb,
    const float* __restrict__ prW, const float* __restrict__ prb,
    float* __restrict__ outbuf, float* __restrict__ ta)
{
    __shared__ float lds[MB][256];
    __shared__ float clds[MB][HD];
    __shared__ float scs[MB];
    __shared__ float dgs[MB];
    __shared__ float red[4][8];
    const int base = blockIdx.x*MB, tid = threadIdx.x;

    #pragma unroll
    for (int i = 0; i < 8; ++i){
        int fidx = i*256 + tid;
        int t = fidx >> 6, c = fidx & 63;
        float4 v = {0.f,0.f,0.f,0.f};
        if (base + t < NN){
            const float* srcp = (c < 32) ? &h[(size_t)(base+t)*HD + c*4]
                                         : &aggr[(size_t)(base+t)*HD + (c-32)*4];
            v = *(const float4*)srcp;
        }
        *(float4*)&lds[t][c*4] = v;
    }
    if (tid < MB) scs[tid] = (base+tid < NN) ? imp[base+tid] : 0.f;
    else if (tid < 2*MB){
        int t = tid - MB;
        dgs[t] = (base+t < NN) ? (float)deg[base+t] : 0.f;
    }
    __syncthreads();

    const int rg = tid >> 6, c0 = (tid & 63)*2, r0 = rg*8;

    // conv = [h|aggr] @ Wf + deg*bc + ub
    float accA[8], accB[8];
    {
        float b0 = ub[c0], b1 = ub[c0+1];
        float bc0 = bcv[c0], bc1 = bcv[c0+1];
        #pragma unroll
        for (int r = 0; r < 8; ++r){
            accA[r] = fmaf(dgs[r0+r], bc0, b0);
            accB[r] = fmaf(dgs[r0+r], bc1, b1);
        }
    }
    #pragma unroll 2
    for (int k4 = 0; k4 < 64; ++k4){
        float2 w0 = *(const float2*)&Wf[(size_t)(k4*4+0)*HD + c0];
        float2 w1 = *(const float2*)&Wf[(size_t)(k4*4+1)*HD + c0];
        float2 w2 = *(const float2*)&Wf[(size_t)(k4*4+2)*HD + c0];
        float2 w3 = *(const float2*)&Wf[(size_t)(k4*4+3)*HD + c0];
        #pragma unroll
        for (int r = 0; r < 8; ++r){
            const float4 a = *(const float4*)&lds[r0+r][k4*4];
            accA[r] = fmaf(a.x,w0.x, fmaf(a.y,w1.x, fmaf(a.z,w2.x, fmaf(a.w,w3.x, accA[r]))));
            accB[r] = fmaf(a.x,w0.y, fmaf(a.y,w1.y, fmaf(a.z,w2.y, fmaf(a.w,w3.y, accB[r]))));
        }
    }
    #pragma unroll
    for (int r = 0; r < 8; ++r)
        *(float2*)&clds[r0+r][c0] = make_float2(accA[r], accB[r]);
    __syncthreads();

    // gate z = conv@gW_top + imp*gW[128] + gb
    float zA[8], zB[8];
    {
        float gwl0 = gW[(size_t)HD*HD + c0], gwl1 = gW[(size_t)HD*HD + c0+1];
        float gb0 = gb[c0], gb1 = gb[c0+1];
        #pragma unroll
        for (int r = 0; r < 8; ++r){
            zA[r] = fmaf(scs[r0+r], gwl0, gb0);
            zB[r] = fmaf(scs[r0+r], gwl1, gb1);
        }
    }
    #pragma unroll 2
    for (int k4 = 0; k4 < 32; ++k4){
        float2 w0 = *(const float2*)&gW[(size_t)(k4*4+0)*HD + c0];
        float2 w1 = *(const float2*)&gW[(size_t)(k4*4+1)*HD + c0];
        float2 w2 = *(const float2*)&gW[(size_t)(k4*4+2)*HD + c0];
        float2 w3 = *(const float2*)&gW[(size_t)(k4*4+3)*HD + c0];
        #pragma unroll
        for (int r = 0; r < 8; ++r){
            const float4 a = *(const float4*)&clds[r0+r][k4*4];
            zA[r] = fmaf(a.x,w0.x, fmaf(a.y,w1.x, fmaf(a.z,w2.x, fmaf(a.w,w3.x, zA[r]))));
            zB[r] = fmaf(a.x,w0.y, fmaf(a.y,w1.y, fmaf(a.z,w2.y, fmaf(a.w,w3.y, zB[r]))));
        }
    }

    // epilogue: gate mix, store out, prop partials
    float prw0 = prW[c0], prw1 = prW[c0+1];
    float psum[8];
    #pragma unroll
    for (int r = 0; r < 8; ++r){
        float g0 = 1.f/(1.f + expf(-zA[r]));
        float g1 = 1.f/(1.f + expf(-zB[r]));
        float2 cv = *(const float2*)&clds[r0+r][c0];
        float2 hv = *(const float2*)&lds[r0+r][c0];
        float o0 = g0*cv.x + (1.f - g0)*hv.x;
        float o1 = g1*cv.y + (1.f - g1)*hv.y;
        if (base + r0 + r < NN)
            *(float2*)&outbuf[(size_t)(base+r0+r)*HD + c0] = make_float2(o0, o1);
        psum[r] = o0*prw0 + o1*prw1;
    }
    int lane = tid & 63;
    #pragma unroll
    for (int r = 0; r < 8; ++r){
        float v = psum[r];
        #pragma unroll
        for (int off = 32; off > 0; off >>= 1) v += __shfl_xor(v, off);
        if (lane == 0) red[rg][r] = v;
    }
    __syncthreads();
    if (tid < MB && base + tid < NN)
        ta[base+tid] = 0.9f*scs[tid] + 0.1f*(red[tid>>3][tid&7] + prb[0]);
}

// ---------- CSR build (by dst) ----------
__global__ void k_deg(const int* __restrict__ dst, int* deg){
    int e = blockIdx.x*blockDim.x + threadIdx.x;
    if (e < NE) atomicAdd(&deg[dst[e]], 1);
}

__global__ __launch_bounds__(1024) void k_scan(const int* __restrict__ deg,
                                               int* __restrict__ rowstart){
    __shared__ int wtot[16];
    __shared__ int woff[16];
    __shared__ int carry;
    int tid = threadIdx.x, lane = tid & 63, wv = tid >> 6;
    if (tid == 0) carry = 0;
    __syncthreads();
    for (int base = 0; base < NN; base += 1024){
        int i = base + tid;
        int v = (i < NN) ? deg[i] : 0;
        int x = v;
        #pragma unroll
        for (int off = 1; off < 64; off <<= 1){
            int y = __shfl_up(x, off);
            if (lane >= off) x += y;
        }
        if (lane == 63) wtot[wv] = x;
        __syncthreads();
        if (tid == 0){
            int a = carry;
            for (int w2 = 0; w2 < 16; ++w2){ woff[w2] = a; a += wtot[w2]; }
            carry = a;
        }
        __syncthreads();
        if (i < NN) rowstart[i] = woff[wv] + x - v;   // exclusive
    }
    __syncthreads();
    if (tid == 0) rowstart[NN] = carry;
}

__global__ void k_copy_int(const int* __restrict__ a, int* __restrict__ b, int n){
    int i = blockIdx.x*blockDim.x + threadIdx.x;
    if (i < n) b[i] = a[i];
}

__global__ void k_fill(const int* __restrict__ src, const int* __restrict__ dst,
                       int* cursor, int* __restrict__ csr){
    int e = blockIdx.x*blockDim.x + threadIdx.x;
    if (e < NE){
        int d = dst[e];
        int p = atomicAdd(&cursor[d], 1);
        csr[p] = src[e];
    }
}

// aggr[node] = sum over in-edges of h[src]; 32 lanes/node, 4-edge ILP
__global__ __launch_bounds__(256) void k_aggregate(
    const float* __restrict__ hm, const int* __restrict__ rowstart,
    const int* __restrict__ csr, float* __restrict__ aggr)
{
    int node = blockIdx.x*8 + (threadIdx.x >> 5);
    int lane = threadIdx.x & 31;
    float4 a0 = {0.f,0.f,0.f,0.f}, a1 = a0, a2 = a0, a3 = a0;
    int e0 = rowstart[node], e1 = rowstart[node+1];
    int e = e0;
    for (; e + 3 < e1; e += 4){
        int s0 = csr[e], s1 = csr[e+1], s2 = csr[e+2], s3 = csr[e+3];
        const float4 v0 = *(const float4*)&hm[(size_t)s0*HD + lane*4];
        const float4 v1 = *(const float4*)&hm[(size_t)s1*HD + lane*4];
        const float4 v2 = *(const float4*)&hm[(size_t)s2*HD + lane*4];
        const float4 v3 = *(const float4*)&hm[(size_t)s3*HD + lane*4];
        a0.x += v0.x; a0.y += v0.y; a0.z += v0.z; a0.w += v0.w;
        a1.x += v1.x; a1.y += v1.y; a1.z += v1.z; a1.w += v1.w;
        a2.x += v2.x; a2.y += v2.y; a2.z += v2.z; a2.w += v2.w;
        a3.x += v3.x; a3.y += v3.y; a3.z += v3.z; a3.w += v3.w;
    }
    for (; e < e1; ++e){
        int s0 = csr[e];
        const float4 v0 = *(const float4*)&hm[(size_t)s0*HD + lane*4];
        a0.x += v0.x; a0.y += v0.y; a0.z += v0.z; a0.w += v0.w;
    }
    a0.x += a1.x + a2.x + a3.x; a0.y += a1.y + a2.y + a3.y;
    a0.z += a1.z + a2.z + a3.z; a0.w += a1.w + a2.w + a3.w;
    *(float4*)&aggr[(size_t)node*HD + lane*4] = a0;
}

// ---------- fused graph-norm (4 col-slices per graph) + importance chain ----
__global__ __launch_bounds__(256) void k_gnorm(
    const float* __restrict__ v, const int* __restrict__ gstart,
    const float* __restrict__ nw, const float* __restrict__ nb,
    const float* __restrict__ na, float* __restrict__ hout,
    const float* __restrict__ tsrc, float* __restrict__ tdst)
{
    int g = blockIdx.x;
    int part = blockIdx.y;
    int s = gstart[g], n = gstart[g+1] - s;
    int tid = threadIdx.x;

    if (part == 4){
        // importance chain: t=norm(tsrc); t=(t<0.1?0:t); tdst=norm(t)
        __shared__ float sv[1024];
        __shared__ float red[8];
        float lmn = 3.4e38f, lmx = -3.4e38f;
        for (int i = tid; i < n; i += 256){
            float val = tsrc[s+i]; sv[i] = val;
            lmn = fminf(lmn, val); lmx = fmaxf(lmx, val);
        }
        float lo, hi;
        block_minmax(lmn, lmx, red, lo, hi);
        float inv = 1.f/(hi - lo + 1e-8f);
        lmn = 3.4e38f; lmx = -3.4e38f;
        for (int i = tid; i < n; i += 256){
            float t2 = (sv[i] - lo)*inv;
            if (t2 < 0.1f) t2 = 0.f;
            sv[i] = t2;
            lmn = fminf(lmn, t2); lmx = fmaxf(lmx, t2);
        }
        float lo2, hi2;
        block_minmax(lmn, lmx, red, lo2, hi2);
        float inv2 = 1.f/(hi2 - lo2 + 1e-8f);
        for (int i = tid; i < n; i += 256) tdst[s+i] = (sv[i] - lo2)*inv2;
        return;
    }

    __shared__ float4 rs1[32][8];
    __shared__ float4 rs2[32][8];
    __shared__ float amv[32], scv[32], nbv[32];
    int rg = tid >> 3, c4l = tid & 7;
    size_t coff = (size_t)part*32 + c4l*4;
    float4 s1 = {0.f,0.f,0.f,0.f}, s2 = {0.f,0.f,0.f,0.f};
    for (int i = rg; i < n; i += 32){
        const float4 vv = *(const float4*)&v[(size_t)(s+i)*HD + coff];
        s1.x += vv.x; s1.y += vv.y; s1.z += vv.z; s1.w += vv.w;
        s2.x += vv.x*vv.x; s2.y += vv.y*vv.y; s2.z += vv.z*vv.z; s2.w += vv.w*vv.w;
    }
    rs1[rg][c4l] = s1; rs2[rg][c4l] = s2;
    __syncthreads();
    if (tid < 8){
        float4 t1 = {0.f,0.f,0.f,0.f}, t2 = {0.f,0.f,0.f,0.f};
        for (int r = 0; r < 32; ++r){
            float4 a = rs1[r][tid]; float4 b = rs2[r][tid];
            t1.x += a.x; t1.y += a.y; t1.z += a.z; t1.w += a.w;
            t2.x += b.x; t2.y += b.y; t2.z += b.z; t2.w += b.w;
        }
        float fn = (float)n;
        float S1[4] = {t1.x,t1.y,t1.z,t1.w};
        float S2[4] = {t2.x,t2.y,t2.z,t2.w};
        #pragma unroll
        for (int e = 0; e < 4; ++e){
            int j = part*32 + tid*4 + e;
            float m = S1[e]/fn;
            float aj = na[j];
            float var = S2[e]/fn - (2.f*aj - aj*aj)*m*m;
            float stdv = sqrtf(var + 1e-5f);
            amv[tid*4+e] = aj*m;
            scv[tid*4+e] = nw[j]/stdv;
            nbv[tid*4+e] = nb[j];
        }
    }
    __syncthreads();
    const float4 am4 = *(const float4*)&amv[c4l*4];
    const float4 sc4 = *(const float4*)&scv[c4l*4];
    const float4 nb4 = *(const float4*)&nbv[c4l*4];
    for (int i = rg; i < n; i += 32){
        const float4 vv = *(const float4*)&v[(size_t)(s+i)*HD + coff];
        float4 r;
        r.x = fmaxf((vv.x - am4.x)*sc4.x + nb4.x, 0.f);
        r.y = fmaxf((vv.y - am4.y)*sc4.y + nb4.y, 0.f);
        r.z = fmaxf((vv.z - am4.z)*sc4.z + nb4.z, 0.f);
        r.w = fmaxf((vv.w - am4.w)*sc4.w + nb4.w, 0.f);
        *(float4*)&hout[(size_t)(s+i)*HD + coff] = r;
    }
}

// ---------- fused final: column-sum + logits GEMM + final importance --------
__global__ __launch_bounds__(1024) void k_logits(
    const float* __restrict__ h, const int* __restrict__ gstart,
    const float* __restrict__ fW, const float* __restrict__ fb,
    const float* __restrict__ imp0, const float* __restrict__ impf,
    float* __restrict__ outp)
{
    __shared__ float4 rs1[32][32];
    __shared__ float gsum[HD];
    __shared__ float redn[32];
    int g = blockIdx.x;
    int s = gstart[g], n = gstart[g+1] - s;
    int tid = threadIdx.x;
    int c4 = tid & 31, rg = tid >> 5;
    float4 s1 = {0.f,0.f,0.f,0.f};
    for (int i = rg; i < n; i += 32){
        const float4 vv = *(const float4*)&h[(size_t)(s+i)*HD + c4*4];
        s1.x += vv.x; s1.y += vv.y; s1.z += vv.z; s1.w += vv.w;
    }
    rs1[rg][c4] = s1;
    __syncthreads();
    if (tid < 32){
        float4 t1 = {0.f,0.f,0.f,0.f};
        for (int r = 0; r < 32; ++r){
            float4 a = rs1[r][tid];
            t1.x += a.x; t1.y += a.y; t1.z += a.z; t1.w += a.w;
        }
        gsum[tid*4+0] = t1.x; gsum[tid*4+1] = t1.y;
        gsum[tid*4+2] = t1.z; gsum[tid*4+3] = t1.w;
    }
    __syncthreads();
    if (tid < 32){
        int o = tid;
        float acc = 0.f;
        for (int k = 0; k < HD; ++k) acc = fmaf(gsum[k], fW[k*32 + o], acc);
        outp[g*32 + o] = acc/(float)n + fb[o];
    }
    // final importance = normalize(imp0 + impf) over this graph
    float val = 0.f;
    bool has = (tid < n);
    float lmn = 3.4e38f, lmx = -3.4e38f;
    if (has){ val = imp0[s+tid] + impf[s+tid]; lmn = val; lmx = val; }
    #pragma unroll
    for (int off = 32; off > 0; off >>= 1){
        lmn = fminf(lmn, __shfl_xor(lmn, off));
        lmx = fmaxf(lmx, __shfl_xor(lmx, off));
    }
    int wv = tid >> 6, lane = tid & 63;
    if (lane == 0){ redn[wv] = lmn; redn[16+wv] = lmx; }
    __syncthreads();
    float lo = redn[0], hi = redn[16];
    for (int r2 = 1; r2 < 16; ++r2){
        lo = fminf(lo, redn[r2]); hi = fmaxf(hi, redn[16+r2]);
    }
    if (has) outp[NG*32 + s + tid] = (val - lo)/(hi - lo + 1e-8f);
}

extern "C" void kernel_launch(void* const* d_in, const int* in_sizes, int n_in,
                              void* d_out, int out_size, void* d_ws, size_t ws_size,
                              hipStream_t stream){
    const float* x    = (const float*)d_in[0];
    const float* imp0 = (const float*)d_in[2];
    const float* pW   = (const float*)d_in[3];
    const float* pb   = (const float*)d_in[4];
    const float* iW   = (const float*)d_in[5];
    const float* ib   = (const float*)d_in[6];
    const float* msgW = (const float*)d_in[7];
    const float* msgb = (const float*)d_in[8];
    const float* updW = (const float*)d_in[9];
    const float* updb = (const float*)d_in[10];
    const float* gWt  = (const float*)d_in[11];
    const float* gb   = (const float*)d_in[12];
    const float* prW  = (const float*)d_in[13];
    const float* prb  = (const float*)d_in[14];
    const float* nw   = (const float*)d_in[15];
    const float* nb   = (const float*)d_in[16];
    const float* na   = (const float*)d_in[17];
    const float* fW   = (const float*)d_in[18];
    const float* fb   = (const float*)d_in[19];
    const int* eidx   = (const int*)d_in[20];
    const int* batch  = (const int*)d_in[21];
    const int* esrc = eidx;
    const int* edst = eidx + NE;
    float* outp = (float*)d_out;

    char* w = (char*)d_ws;
    size_t off = 0;
    auto alloc = [&](size_t bytes)->char*{
        char* p = w + off;
        off += (bytes + 255) & ~(size_t)255;
        return p;
    };
    float* h     = (float*)alloc((size_t)NN*HD*4);
    float* aggB  = (float*)alloc((size_t)NN*HD*4);
    float* outA  = (float*)alloc((size_t)NN*HD*4);
    float* ta    = (float*)alloc((size_t)NN*4);
    float* imp   = (float*)alloc((size_t)NN*4);
    float* W0    = (float*)alloc((size_t)(FT+1)*HD*4);
    float* b0    = (float*)alloc((size_t)HD*4);
    float* Wf    = (float*)alloc((size_t)NLAYERS*2*HD*HD*4);
    float* bcv   = (float*)alloc((size_t)NLAYERS*HD*4);
    int* gstart  = (int*)alloc((size_t)(NG+1)*4);
    int* deg     = (int*)alloc((size_t)NN*4);
    int* rowst   = (int*)alloc((size_t)(NN+1)*4);
    int* cursor  = (int*)alloc((size_t)NN*4);
    int* csr     = (int*)alloc((size_t)NE*4);

    // graph boundaries
    k_gbounds<<<196, 256, 0, stream>>>(batch, gstart);

    // CSR by dst
    hipMemsetAsync(deg, 0, NN*4, stream);
    k_deg<<<3125, 256, 0, stream>>>(edst, deg);
    k_scan<<<1, 1024, 0, stream>>>(deg, rowst);
    k_copy_int<<<196, 256, 0, stream>>>(rowst, cursor, NN);
    k_fill<<<3125, 256, 0, stream>>>(esrc, edst, cursor, csr);

    // weight folds
    k_fold_init<<<1, 128, 0, stream>>>(pW, pb, iW, ib, W0, b0);
    for (int l = 0; l < NLAYERS; ++l){
        k_fold_layer<<<257, 128, 0, stream>>>(
            msgW + (size_t)l*HD*HD, updW + (size_t)l*2*HD*HD,
            msgb + (size_t)l*HD, Wf + (size_t)l*2*HD*HD, bcv + (size_t)l*HD);
    }

    // importance = normalize(imp0); h = init GEMM
    k_norm_graph<<<NG, 256, 0, stream>>>(imp0, gstart, imp);
    k_init<<<NBLK, 256, 0, stream>>>(x, imp, W0, b0, h);

    for (int l = 0; l < NLAYERS; ++l){
        k_aggregate<<<6250, 256, 0, stream>>>(h, rowst, csr, aggB);
        k_layer<<<NBLK, 256, 0, stream>>>(
            h, aggB, imp, deg,
            Wf + (size_t)l*2*HD*HD, bcv + (size_t)l*HD,
            updb + (size_t)l*HD, gWt + (size_t)l*(HD+1)*HD, gb + (size_t)l*HD,
            prW + (size_t)l*HD, prb + l, outA, ta);
        // graph-norm (4 col slices) + importance chain (part 4) in one launch
        k_gnorm<<<dim3(NG,5), 256, 0, stream>>>(outA, gstart,
            nw + (size_t)l*HD, nb + (size_t)l*HD, na + (size_t)l*HD, h, ta, imp);
    }

    // logits + final importance
    k_logits<<<NG, 1024, 0, stream>>>(h, gstart, fW, fb, imp0, imp, outp);
}

// Round 5
// 705.667 us; speedup vs baseline: 6.4134x; 1.0381x over previous
//
#include <hip/hip_runtime.h>
#include <cstdint>

#define NN 50000
#define NE 800000
#define NG 64
#define HD 128
#define FT 64
#define NLAYERS 3
#define MB 32
#define NBLK 1563   // ceil(NN/MB)

// ---------- graph boundaries (batch is sorted contiguous runs) ----------
__global__ void k_gbounds(const int* __restrict__ batch, int* __restrict__ gstart){
    int i = blockIdx.x*blockDim.x + threadIdx.x;
    if (i >= NN) return;
    int g = batch[i];
    if (i == 0){ for (int q = 0; q <= g; ++q) gstart[q] = 0; }
    else { int gp = batch[i-1]; for (int q = gp+1; q <= g; ++q) gstart[q] = i; }
    if (i == NN-1){ for (int q = g+1; q <= NG; ++q) gstart[q] = NN; }
}

// ---------- block-wide min/max reduce helper (256 threads = 4 waves) ----------
__device__ __forceinline__ void block_minmax(float lmn, float lmx, float* red,
                                             float& omn, float& omx){
    #pragma unroll
    for (int off = 32; off > 0; off >>= 1){
        lmn = fminf(lmn, __shfl_xor(lmn, off));
        lmx = fmaxf(lmx, __shfl_xor(lmx, off));
    }
    int wave = threadIdx.x >> 6;
    if ((threadIdx.x & 63) == 0){ red[wave] = lmn; red[4+wave] = lmx; }
    __syncthreads();
    omn = fminf(fminf(red[0], red[1]), fminf(red[2], red[3]));
    omx = fmaxf(fmaxf(red[4], red[5]), fmaxf(red[6], red[7]));
    __syncthreads();
}

// ---------- per-graph normalize (initial importance only) ----------
__global__ __launch_bounds__(256) void k_norm_graph(
    const float* __restrict__ va, const int* __restrict__ gstart,
    float* __restrict__ out)
{
    __shared__ float sv[1024];
    __shared__ float red[8];
    int g = blockIdx.x;
    int s = gstart[g], n = gstart[g+1] - s;
    int tid = threadIdx.x;
    float lmn = 3.4e38f, lmx = -3.4e38f;
    for (int i = tid; i < n; i += 256){
        float v = va[s+i];
        sv[i] = v;
        lmn = fminf(lmn, v); lmx = fmaxf(lmx, v);
    }
    float lo, hi;
    block_minmax(lmn, lmx, red, lo, hi);
    float inv = 1.f/(hi - lo + 1e-8f);
    for (int i = tid; i < n; i += 256) out[s+i] = (sv[i] - lo)*inv;
}

// Fold imp_proj into init_W: W0 is (FT+1) x HD, b0 = init_b + pb @ init_W[FT:]
__global__ void k_fold_init(const float* __restrict__ pW, const float* __restrict__ pb,
                            const float* __restrict__ iW, const float* __restrict__ ib,
                            float* __restrict__ W0, float* __restrict__ b0){
    int j = threadIdx.x;
    for (int k = 0; k < FT; ++k) W0[k*HD + j] = iW[k*HD + j];
    float w2 = 0.f, b2 = 0.f;
    for (int k = 0; k < HD; ++k){
        float w = iW[(FT + k)*HD + j];
        w2 += pW[k]*w;
        b2 += pb[k]*w;
    }
    W0[FT*HD + j] = w2;
    b0[j] = ib[j] + b2;
}

// Wf(256x128) = [uW_top ; msg_W @ uW_bot], bcv = msg_b @ uW_bot.
// grid (257, NLAYERS) x 128.
__global__ void k_fold_layer(const float* __restrict__ msgW, const float* __restrict__ updW,
                             const float* __restrict__ msgb,
                             float* __restrict__ WfA, float* __restrict__ bcvA){
    int l = blockIdx.y;
    const float* mW  = msgW + (size_t)l*HD*HD;
    const float* uW  = updW + (size_t)l*2*HD*HD;
    const float* mb  = msgb + (size_t)l*HD;
    float* Wf  = WfA  + (size_t)l*2*HD*HD;
    float* bcv = bcvA + (size_t)l*HD;
    int j = threadIdx.x;
    int r = blockIdx.x;
    if (r < HD){
        Wf[(size_t)r*HD + j] = uW[(size_t)r*HD + j];
    } else if (r < 2*HD){
        int rr = r - HD;
        const float* uWbot = uW + (size_t)HD*HD;
        float acc = 0.f;
        for (int k = 0; k < HD; ++k)
            acc = fmaf(mW[(size_t)rr*HD + k], uWbot[(size_t)k*HD + j], acc);
        Wf[(size_t)r*HD + j] = acc;
    } else {
        const float* uWbot = uW + (size_t)HD*HD;
        float acc = 0.f;
        for (int k = 0; k < HD; ++k)
            acc = fmaf(mb[k], uWbot[(size_t)k*HD + j], acc);
        bcv[j] = acc;
    }
}

// ---------- init GEMM: h = x @ W0[0:64] + imp*W0[64] + b0 ----------
// 256 thr, 32 nodes/block, thread tile 4 rows x 4 cols
__global__ __launch_bounds__(256) void k_init(
    const float* __restrict__ x, const float* __restrict__ imp,
    const float* __restrict__ W0, const float* __restrict__ b0v,
    float* __restrict__ h)
{
    __shared__ float lds[MB][FT];
    __shared__ float scs[MB];
    int base = blockIdx.x*MB, tid = threadIdx.x;
    #pragma unroll
    for (int i = 0; i < 2; ++i){
        int fidx = i*256 + tid;
        int t = fidx >> 4, c = fidx & 15;
        float4 v = {0.f,0.f,0.f,0.f};
        if (base + t < NN) v = *(const float4*)&x[(size_t)(base+t)*FT + c*4];
        *(float4*)&lds[t][c*4] = v;
    }
    if (tid < MB) scs[tid] = (base+tid < NN) ? imp[base+tid] : 0.f;
    __syncthreads();

    const int cg = tid & 31, rg = tid >> 5;
    const int c0 = cg*4, r0 = rg*4;
    const float4 wl4 = *(const float4*)&W0[(size_t)FT*HD + c0];
    const float4 b4  = *(const float4*)&b0v[c0];
    float acc[4][4];
    #pragma unroll
    for (int r = 0; r < 4; ++r){
        float s = scs[r0+r];
        acc[r][0] = fmaf(s, wl4.x, b4.x); acc[r][1] = fmaf(s, wl4.y, b4.y);
        acc[r][2] = fmaf(s, wl4.z, b4.z); acc[r][3] = fmaf(s, wl4.w, b4.w);
    }
    for (int k4 = 0; k4 < 16; ++k4){
        const float4 w0 = *(const float4*)&W0[(size_t)(k4*4+0)*HD + c0];
        const float4 w1 = *(const float4*)&W0[(size_t)(k4*4+1)*HD + c0];
        const float4 w2 = *(const float4*)&W0[(size_t)(k4*4+2)*HD + c0];
        const float4 w3 = *(const float4*)&W0[(size_t)(k4*4+3)*HD + c0];
        #pragma unroll
        for (int r = 0; r < 4; ++r){
            const float4 a = *(const float4*)&lds[r0+r][k4*4];
            acc[r][0]=fmaf(a.x,w0.x,fmaf(a.y,w1.x,fmaf(a.z,w2.x,fmaf(a.w,w3.x,acc[r][0]))));
            acc[r][1]=fmaf(a.x,w0.y,fmaf(a.y,w1.y,fmaf(a.z,w2.y,fmaf(a.w,w3.y,acc[r][1]))));
            acc[r][2]=fmaf(a.x,w0.z,fmaf(a.y,w1.z,fmaf(a.z,w2.z,fmaf(a.w,w3.z,acc[r][2]))));
            acc[r][3]=fmaf(a.x,w0.w,fmaf(a.y,w1.w,fmaf(a.z,w2.w,fmaf(a.w,w3.w,acc[r][3]))));
        }
    }
    #pragma unroll
    for (int r = 0; r < 4; ++r)
        if (base + r0 + r < NN)
            *(float4*)&h[(size_t)(base+r0+r)*HD + c0] =
                make_float4(acc[r][0], acc[r][1], acc[r][2], acc[r][3]);
}

// ---------- per-layer mega kernel (4x4 reg tiles) ----------
__global__ __launch_bounds__(256) void k_layer(
    const float* __restrict__ h, const float* __restrict__ aggr,
    const float* __restrict__ imp, const int* __restrict__ deg,
    const float* __restrict__ Wf, const float* __restrict__ bcv,
    const float* __restrict__ ub,
    const float* __restrict__ gW, const float* __restrict__ gb,
    const float* __restrict__ prW, const float* __restrict__ prb,
    float* __restrict__ outbuf, float* __restrict__ ta)
{
    __shared__ float lds[MB][256];
    __shared__ float clds[MB][HD];
    __shared__ float scs[MB];
    __shared__ float dgs[MB];
    __shared__ float red[8][4];
    const int base = blockIdx.x*MB, tid = threadIdx.x;

    #pragma unroll
    for (int i = 0; i < 8; ++i){
        int fidx = i*256 + tid;
        int t = fidx >> 6, c = fidx & 63;
        float4 v = {0.f,0.f,0.f,0.f};
        if (base + t < NN){
            const float* srcp = (c < 32) ? &h[(size_t)(base+t)*HD + c*4]
                                         : &aggr[(size_t)(base+t)*HD + (c-32)*4];
            v = *(const float4*)srcp;
        }
        *(float4*)&lds[t][c*4] = v;
    }
    if (tid < MB) scs[tid] = (base+tid < NN) ? imp[base+tid] : 0.f;
    else if (tid < 2*MB){
        int t = tid - MB;
        dgs[t] = (base+t < NN) ? (float)deg[base+t] : 0.f;
    }
    __syncthreads();

    const int cg = tid & 31, rg = tid >> 5;
    const int c0 = cg*4, r0 = rg*4;

    // conv = [h|aggr] @ Wf + deg*bc + ub
    const float4 bc4 = *(const float4*)&bcv[c0];
    const float4 ub4 = *(const float4*)&ub[c0];
    float acc[4][4];
    #pragma unroll
    for (int r = 0; r < 4; ++r){
        float d = dgs[r0+r];
        acc[r][0] = fmaf(d, bc4.x, ub4.x); acc[r][1] = fmaf(d, bc4.y, ub4.y);
        acc[r][2] = fmaf(d, bc4.z, ub4.z); acc[r][3] = fmaf(d, bc4.w, ub4.w);
    }
    for (int k4 = 0; k4 < 64; ++k4){
        const float4 w0 = *(const float4*)&Wf[(size_t)(k4*4+0)*HD + c0];
        const float4 w1 = *(const float4*)&Wf[(size_t)(k4*4+1)*HD + c0];
        const float4 w2 = *(const float4*)&Wf[(size_t)(k4*4+2)*HD + c0];
        const float4 w3 = *(const float4*)&Wf[(size_t)(k4*4+3)*HD + c0];
        #pragma unroll
        for (int r = 0; r < 4; ++r){
            const float4 a = *(const float4*)&lds[r0+r][k4*4];
            acc[r][0]=fmaf(a.x,w0.x,fmaf(a.y,w1.x,fmaf(a.z,w2.x,fmaf(a.w,w3.x,acc[r][0]))));
            acc[r][1]=fmaf(a.x,w0.y,fmaf(a.y,w1.y,fmaf(a.z,w2.y,fmaf(a.w,w3.y,acc[r][1]))));
            acc[r][2]=fmaf(a.x,w0.z,fmaf(a.y,w1.z,fmaf(a.z,w2.z,fmaf(a.w,w3.z,acc[r][2]))));
            acc[r][3]=fmaf(a.x,w0.w,fmaf(a.y,w1.w,fmaf(a.z,w2.w,fmaf(a.w,w3.w,acc[r][3]))));
        }
    }
    #pragma unroll
    for (int r = 0; r < 4; ++r)
        *(float4*)&clds[r0+r][c0] = make_float4(acc[r][0],acc[r][1],acc[r][2],acc[r][3]);
    __syncthreads();

    // gate z = conv@gW_top + imp*gW[128] + gb
    const float4 gwl = *(const float4*)&gW[(size_t)HD*HD + c0];
    const float4 gb4 = *(const float4*)&gb[c0];
    float z[4][4];
    #pragma unroll
    for (int r = 0; r < 4; ++r){
        float s = scs[r0+r];
        z[r][0] = fmaf(s, gwl.x, gb4.x); z[r][1] = fmaf(s, gwl.y, gb4.y);
        z[r][2] = fmaf(s, gwl.z, gb4.z); z[r][3] = fmaf(s, gwl.w, gb4.w);
    }
    for (int k4 = 0; k4 < 32; ++k4){
        const float4 w0 = *(const float4*)&gW[(size_t)(k4*4+0)*HD + c0];
        const float4 w1 = *(const float4*)&gW[(size_t)(k4*4+1)*HD + c0];
        const float4 w2 = *(const float4*)&gW[(size_t)(k4*4+2)*HD + c0];
        const float4 w3 = *(const float4*)&gW[(size_t)(k4*4+3)*HD + c0];
        #pragma unroll
        for (int r = 0; r < 4; ++r){
            const float4 a = *(const float4*)&clds[r0+r][k4*4];
            z[r][0]=fmaf(a.x,w0.x,fmaf(a.y,w1.x,fmaf(a.z,w2.x,fmaf(a.w,w3.x,z[r][0]))));
            z[r][1]=fmaf(a.x,w0.y,fmaf(a.y,w1.y,fmaf(a.z,w2.y,fmaf(a.w,w3.y,z[r][1]))));
            z[r][2]=fmaf(a.x,w0.z,fmaf(a.y,w1.z,fmaf(a.z,w2.z,fmaf(a.w,w3.z,z[r][2]))));
            z[r][3]=fmaf(a.x,w0.w,fmaf(a.y,w1.w,fmaf(a.z,w2.w,fmaf(a.w,w3.w,z[r][3]))));
        }
    }

    // epilogue: gate mix, store out, prop partials (conv still in acc regs)
    const float4 pr4 = *(const float4*)&prW[c0];
    float psum[4];
    #pragma unroll
    for (int r = 0; r < 4; ++r){
        const float4 hv = *(const float4*)&lds[r0+r][c0];
        float g0 = 1.f/(1.f + expf(-z[r][0]));
        float g1 = 1.f/(1.f + expf(-z[r][1]));
        float g2 = 1.f/(1.f + expf(-z[r][2]));
        float g3 = 1.f/(1.f + expf(-z[r][3]));
        float o0 = g0*acc[r][0] + (1.f-g0)*hv.x;
        float o1 = g1*acc[r][1] + (1.f-g1)*hv.y;
        float o2 = g2*acc[r][2] + (1.f-g2)*hv.z;
        float o3 = g3*acc[r][3] + (1.f-g3)*hv.w;
        if (base + r0 + r < NN)
            *(float4*)&outbuf[(size_t)(base+r0+r)*HD + c0] = make_float4(o0,o1,o2,o3);
        psum[r] = o0*pr4.x + o1*pr4.y + o2*pr4.z + o3*pr4.w;
    }
    #pragma unroll
    for (int r = 0; r < 4; ++r){
        float v = psum[r];
        #pragma unroll
        for (int off = 16; off > 0; off >>= 1) v += __shfl_xor(v, off);
        if (cg == 0) red[rg][r] = v;
    }
    __syncthreads();
    if (tid < MB && base + tid < NN)
        ta[base+tid] = 0.9f*scs[tid] + 0.1f*(red[tid>>2][tid&3] + prb[0]);
}

// ---------- CSR build (by dst) ----------
__global__ void k_deg(const int* __restrict__ dst, int* deg){
    int e = blockIdx.x*blockDim.x + threadIdx.x;
    if (e < NE) atomicAdd(&deg[dst[e]], 1);
}

__global__ __launch_bounds__(1024) void k_scan(const int* __restrict__ deg,
                                               int* __restrict__ rowstart){
    __shared__ int wtot[16];
    __shared__ int woff[16];
    __shared__ int carry;
    int tid = threadIdx.x, lane = tid & 63, wv = tid >> 6;
    if (tid == 0) carry = 0;
    __syncthreads();
    for (int base = 0; base < NN; base += 1024){
        int i = base + tid;
        int v = (i < NN) ? deg[i] : 0;
        int x = v;
        #pragma unroll
        for (int off = 1; off < 64; off <<= 1){
            int y = __shfl_up(x, off);
            if (lane >= off) x += y;
        }
        if (lane == 63) wtot[wv] = x;
        __syncthreads();
        if (tid == 0){
            int a = carry;
            for (int w2 = 0; w2 < 16; ++w2){ woff[w2] = a; a += wtot[w2]; }
            carry = a;
        }
        __syncthreads();
        if (i < NN) rowstart[i] = woff[wv] + x - v;   // exclusive
    }
    __syncthreads();
    if (tid == 0) rowstart[NN] = carry;
}

__global__ void k_copy_int(const int* __restrict__ a, int* __restrict__ b, int n){
    int i = blockIdx.x*blockDim.x + threadIdx.x;
    if (i < n) b[i] = a[i];
}

__global__ void k_fill(const int* __restrict__ src, const int* __restrict__ dst,
                       int* cursor, int* __restrict__ csr){
    int e = blockIdx.x*blockDim.x + threadIdx.x;
    if (e < NE){
        int d = dst[e];
        int p = atomicAdd(&cursor[d], 1);
        csr[p] = src[e];
    }
}

// aggr[node] = sum over in-edges of h[src]; 32 lanes/node, 8-edge ILP
__global__ __launch_bounds__(256) void k_aggregate(
    const float* __restrict__ hm, const int* __restrict__ rowstart,
    const int* __restrict__ csr, float* __restrict__ aggr)
{
    int node = blockIdx.x*8 + (threadIdx.x >> 5);
    int lane = threadIdx.x & 31;
    float4 a0 = {0.f,0.f,0.f,0.f}, a1 = a0, a2 = a0, a3 = a0;
    float4 a4 = a0, a5 = a0, a6 = a0, a7 = a0;
    int e0 = rowstart[node], e1 = rowstart[node+1];
    int e = e0;
    for (; e + 7 < e1; e += 8){
        int s0 = csr[e],   s1 = csr[e+1], s2 = csr[e+2], s3 = csr[e+3];
        int s4 = csr[e+4], s5 = csr[e+5], s6 = csr[e+6], s7 = csr[e+7];
        const float4 v0 = *(const float4*)&hm[(size_t)s0*HD + lane*4];
        const float4 v1 = *(const float4*)&hm[(size_t)s1*HD + lane*4];
        const float4 v2 = *(const float4*)&hm[(size_t)s2*HD + lane*4];
        const float4 v3 = *(const float4*)&hm[(size_t)s3*HD + lane*4];
        const float4 v4 = *(const float4*)&hm[(size_t)s4*HD + lane*4];
        const float4 v5 = *(const float4*)&hm[(size_t)s5*HD + lane*4];
        const float4 v6 = *(const float4*)&hm[(size_t)s6*HD + lane*4];
        const float4 v7 = *(const float4*)&hm[(size_t)s7*HD + lane*4];
        a0.x += v0.x; a0.y += v0.y; a0.z += v0.z; a0.w += v0.w;
        a1.x += v1.x; a1.y += v1.y; a1.z += v1.z; a1.w += v1.w;
        a2.x += v2.x; a2.y += v2.y; a2.z += v2.z; a2.w += v2.w;
        a3.x += v3.x; a3.y += v3.y; a3.z += v3.z; a3.w += v3.w;
        a4.x += v4.x; a4.y += v4.y; a4.z += v4.z; a4.w += v4.w;
        a5.x += v5.x; a5.y += v5.y; a5.z += v5.z; a5.w += v5.w;
        a6.x += v6.x; a6.y += v6.y; a6.z += v6.z; a6.w += v6.w;
        a7.x += v7.x; a7.y += v7.y; a7.z += v7.z; a7.w += v7.w;
    }
    for (; e + 3 < e1; e += 4){
        int s0 = csr[e], s1 = csr[e+1], s2 = csr[e+2], s3 = csr[e+3];
        const float4 v0 = *(const float4*)&hm[(size_t)s0*HD + lane*4];
        const float4 v1 = *(const float4*)&hm[(size_t)s1*HD + lane*4];
        const float4 v2 = *(const float4*)&hm[(size_t)s2*HD + lane*4];
        const float4 v3 = *(const float4*)&hm[(size_t)s3*HD + lane*4];
        a0.x += v0.x; a0.y += v0.y; a0.z += v0.z; a0.w += v0.w;
        a1.x += v1.x; a1.y += v1.y; a1.z += v1.z; a1.w += v1.w;
        a2.x += v2.x; a2.y += v2.y; a2.z += v2.z; a2.w += v2.w;
        a3.x += v3.x; a3.y += v3.y; a3.z += v3.z; a3.w += v3.w;
    }
    for (; e < e1; ++e){
        int s0 = csr[e];
        const float4 v0 = *(const float4*)&hm[(size_t)s0*HD + lane*4];
        a0.x += v0.x; a0.y += v0.y; a0.z += v0.z; a0.w += v0.w;
    }
    a0.x += a1.x; a0.y += a1.y; a0.z += a1.z; a0.w += a1.w;
    a2.x += a3.x; a2.y += a3.y; a2.z += a3.z; a2.w += a3.w;
    a4.x += a5.x; a4.y += a5.y; a4.z += a5.z; a4.w += a5.w;
    a6.x += a7.x; a6.y += a7.y; a6.z += a7.z; a6.w += a7.w;
    a0.x += a2.x; a0.y += a2.y; a0.z += a2.z; a0.w += a2.w;
    a4.x += a6.x; a4.y += a6.y; a4.z += a6.z; a4.w += a6.w;
    a0.x += a4.x; a0.y += a4.y; a0.z += a4.z; a0.w += a4.w;
    *(float4*)&aggr[(size_t)node*HD + lane*4] = a0;
}

// ---------- fused graph-norm (4 col-slices per graph) + importance chain ----
__global__ __launch_bounds__(256) void k_gnorm(
    const float* __restrict__ v, const int* __restrict__ gstart,
    const float* __restrict__ nw, const float* __restrict__ nb,
    const float* __restrict__ na, float* __restrict__ hout,
    const float* __restrict__ tsrc, float* __restrict__ tdst)
{
    int g = blockIdx.x;
    int part = blockIdx.y;
    int s = gstart[g], n = gstart[g+1] - s;
    int tid = threadIdx.x;

    if (part == 4){
        __shared__ float sv[1024];
        __shared__ float red[8];
        float lmn = 3.4e38f, lmx = -3.4e38f;
        for (int i = tid; i < n; i += 256){
            float val = tsrc[s+i]; sv[i] = val;
            lmn = fminf(lmn, val); lmx = fmaxf(lmx, val);
        }
        float lo, hi;
        block_minmax(lmn, lmx, red, lo, hi);
        float inv = 1.f/(hi - lo + 1e-8f);
        lmn = 3.4e38f; lmx = -3.4e38f;
        for (int i = tid; i < n; i += 256){
            float t2 = (sv[i] - lo)*inv;
            if (t2 < 0.1f) t2 = 0.f;
            sv[i] = t2;
            lmn = fminf(lmn, t2); lmx = fmaxf(lmx, t2);
        }
        float lo2, hi2;
        block_minmax(lmn, lmx, red, lo2, hi2);
        float inv2 = 1.f/(hi2 - lo2 + 1e-8f);
        for (int i = tid; i < n; i += 256) tdst[s+i] = (sv[i] - lo2)*inv2;
        return;
    }

    __shared__ float4 rs1[32][8];
    __shared__ float4 rs2[32][8];
    __shared__ float amv[32], scv[32], nbv[32];
    int rg = tid >> 3, c4l = tid & 7;
    size_t coff = (size_t)part*32 + c4l*4;
    float4 s1 = {0.f,0.f,0.f,0.f}, s2 = {0.f,0.f,0.f,0.f};
    for (int i = rg; i < n; i += 32){
        const float4 vv = *(const float4*)&v[(size_t)(s+i)*HD + coff];
        s1.x += vv.x; s1.y += vv.y; s1.z += vv.z; s1.w += vv.w;
        s2.x += vv.x*vv.x; s2.y += vv.y*vv.y; s2.z += vv.z*vv.z; s2.w += vv.w*vv.w;
    }
    rs1[rg][c4l] = s1; rs2[rg][c4l] = s2;
    __syncthreads();
    if (tid < 8){
        float4 t1 = {0.f,0.f,0.f,0.f}, t2 = {0.f,0.f,0.f,0.f};
        for (int r = 0; r < 32; ++r){
            float4 a = rs1[r][tid]; float4 b = rs2[r][tid];
            t1.x += a.x; t1.y += a.y; t1.z += a.z; t1.w += a.w;
            t2.x += b.x; t2.y += b.y; t2.z += b.z; t2.w += b.w;
        }
        float fn = (float)n;
        float S1[4] = {t1.x,t1.y,t1.z,t1.w};
        float S2[4] = {t2.x,t2.y,t2.z,t2.w};
        #pragma unroll
        for (int e = 0; e < 4; ++e){
            int j = part*32 + tid*4 + e;
            float m = S1[e]/fn;
            float aj = na[j];
            float var = S2[e]/fn - (2.f*aj - aj*aj)*m*m;
            float stdv = sqrtf(var + 1e-5f);
            amv[tid*4+e] = aj*m;
            scv[tid*4+e] = nw[j]/stdv;
            nbv[tid*4+e] = nb[j];
        }
    }
    __syncthreads();
    const float4 am4 = *(const float4*)&amv[c4l*4];
    const float4 sc4 = *(const float4*)&scv[c4l*4];
    const float4 nb4 = *(const float4*)&nbv[c4l*4];
    for (int i = rg; i < n; i += 32){
        const float4 vv = *(const float4*)&v[(size_t)(s+i)*HD + coff];
        float4 r;
        r.x = fmaxf((vv.x - am4.x)*sc4.x + nb4.x, 0.f);
        r.y = fmaxf((vv.y - am4.y)*sc4.y + nb4.y, 0.f);
        r.z = fmaxf((vv.z - am4.z)*sc4.z + nb4.z, 0.f);
        r.w = fmaxf((vv.w - am4.w)*sc4.w + nb4.w, 0.f);
        *(float4*)&hout[(size_t)(s+i)*HD + coff] = r;
    }
}

// ---------- fused final: column-sum + logits GEMM + final importance --------
__global__ __launch_bounds__(1024) void k_logits(
    const float* __restrict__ h, const int* __restrict__ gstart,
    const float* __restrict__ fW, const float* __restrict__ fb,
    const float* __restrict__ imp0, const float* __restrict__ impf,
    float* __restrict__ outp)
{
    __shared__ float4 rs1[32][32];
    __shared__ float gsum[HD];
    __shared__ float redn[32];
    int g = blockIdx.x;
    int s = gstart[g], n = gstart[g+1] - s;
    int tid = threadIdx.x;
    int c4 = tid & 31, rg = tid >> 5;
    float4 s1 = {0.f,0.f,0.f,0.f};
    for (int i = rg; i < n; i += 32){
        const float4 vv = *(const float4*)&h[(size_t)(s+i)*HD + c4*4];
        s1.x += vv.x; s1.y += vv.y; s1.z += vv.z; s1.w += vv.w;
    }
    rs1[rg][c4] = s1;
    __syncthreads();
    if (tid < 32){
        float4 t1 = {0.f,0.f,0.f,0.f};
        for (int r = 0; r < 32; ++r){
            float4 a = rs1[r][tid];
            t1.x += a.x; t1.y += a.y; t1.z += a.z; t1.w += a.w;
        }
        gsum[tid*4+0] = t1.x; gsum[tid*4+1] = t1.y;
        gsum[tid*4+2] = t1.z; gsum[tid*4+3] = t1.w;
    }
    __syncthreads();
    if (tid < 32){
        int o = tid;
        float acc = 0.f;
        for (int k = 0; k < HD; ++k) acc = fmaf(gsum[k], fW[k*32 + o], acc);
        outp[g*32 + o] = acc/(float)n + fb[o];
    }
    float val = 0.f;
    bool has = (tid < n);
    float lmn = 3.4e38f, lmx = -3.4e38f;
    if (has){ val = imp0[s+tid] + impf[s+tid]; lmn = val; lmx = val; }
    #pragma unroll
    for (int off = 32; off > 0; off >>= 1){
        lmn = fminf(lmn, __shfl_xor(lmn, off));
        lmx = fmaxf(lmx, __shfl_xor(lmx, off));
    }
    int wv = tid >> 6, lane = tid & 63;
    if (lane == 0){ redn[wv] = lmn; redn[16+wv] = lmx; }
    __syncthreads();
    float lo = redn[0], hi = redn[16];
    for (int r2 = 1; r2 < 16; ++r2){
        lo = fminf(lo, redn[r2]); hi = fmaxf(hi, redn[16+r2]);
    }
    if (has) outp[NG*32 + s + tid] = (val - lo)/(hi - lo + 1e-8f);
}

extern "C" void kernel_launch(void* const* d_in, const int* in_sizes, int n_in,
                              void* d_out, int out_size, void* d_ws, size_t ws_size,
                              hipStream_t stream){
    const float* x    = (const float*)d_in[0];
    const float* imp0 = (const float*)d_in[2];
    const float* pW   = (const float*)d_in[3];
    const float* pb   = (const float*)d_in[4];
    const float* iW   = (const float*)d_in[5];
    const float* ib   = (const float*)d_in[6];
    const float* msgW = (const float*)d_in[7];
    const float* msgb = (const float*)d_in[8];
    const float* updW = (const float*)d_in[9];
    const float* updb = (const float*)d_in[10];
    const float* gWt  = (const float*)d_in[11];
    const float* gb   = (const float*)d_in[12];
    const float* prW  = (const float*)d_in[13];
    const float* prb  = (const float*)d_in[14];
    const float* nw   = (const float*)d_in[15];
    const float* nb   = (const float*)d_in[16];
    const float* na   = (const float*)d_in[17];
    const float* fW   = (const float*)d_in[18];
    const float* fb   = (const float*)d_in[19];
    const int* eidx   = (const int*)d_in[20];
    const int* batch  = (const int*)d_in[21];
    const int* esrc = eidx;
    const int* edst = eidx + NE;
    float* outp = (float*)d_out;

    char* w = (char*)d_ws;
    size_t off = 0;
    auto alloc = [&](size_t bytes)->char*{
        char* p = w + off;
        off += (bytes + 255) & ~(size_t)255;
        return p;
    };
    float* h     = (float*)alloc((size_t)NN*HD*4);
    float* aggB  = (float*)alloc((size_t)NN*HD*4);
    float* outA  = (float*)alloc((size_t)NN*HD*4);
    float* ta    = (float*)alloc((size_t)NN*4);
    float* imp   = (float*)alloc((size_t)NN*4);
    float* W0    = (float*)alloc((size_t)(FT+1)*HD*4);
    float* b0    = (float*)alloc((size_t)HD*4);
    float* Wf    = (float*)alloc((size_t)NLAYERS*2*HD*HD*4);
    float* bcv   = (float*)alloc((size_t)NLAYERS*HD*4);
    int* gstart  = (int*)alloc((size_t)(NG+1)*4);
    int* deg     = (int*)alloc((size_t)NN*4);
    int* rowst   = (int*)alloc((size_t)(NN+1)*4);
    int* cursor  = (int*)alloc((size_t)NN*4);
    int* csr     = (int*)alloc((size_t)NE*4);

    // graph boundaries
    k_gbounds<<<196, 256, 0, stream>>>(batch, gstart);

    // CSR by dst
    hipMemsetAsync(deg, 0, NN*4, stream);
    k_deg<<<3125, 256, 0, stream>>>(edst, deg);
    k_scan<<<1, 1024, 0, stream>>>(deg, rowst);
    k_copy_int<<<196, 256, 0, stream>>>(rowst, cursor, NN);
    k_fill<<<3125, 256, 0, stream>>>(esrc, edst, cursor, csr);

    // weight folds
    k_fold_init<<<1, 128, 0, stream>>>(pW, pb, iW, ib, W0, b0);
    k_fold_layer<<<dim3(257, NLAYERS), 128, 0, stream>>>(msgW, updW, msgb, Wf, bcv);

    // importance = normalize(imp0); h = init GEMM
    k_norm_graph<<<NG, 256, 0, stream>>>(imp0, gstart, imp);
    k_init<<<NBLK, 256, 0, stream>>>(x, imp, W0, b0, h);

    for (int l = 0; l < NLAYERS; ++l){
        k_aggregate<<<6250, 256, 0, stream>>>(h, rowst, csr, aggB);
        k_layer<<<NBLK, 256, 0, stream>>>(
            h, aggB, imp, deg,
            Wf + (size_t)l*2*HD*HD, bcv + (size_t)l*HD,
            updb + (size_t)l*HD, gWt + (size_t)l*(HD+1)*HD, gb + (size_t)l*HD,
            prW + (size_t)l*HD, prb + l, outA, ta);
        k_gnorm<<<dim3(NG,5), 256, 0, stream>>>(outA, gstart,
            nw + (size_t)l*HD, nb + (size_t)l*HD, na + (size_t)l*HD, h, ta, imp);
    }

    // logits + final importance
    k_logits<<<NG, 1024, 0, stream>>>(h, gstart, fW, fb, imp0, imp, outp);
}